// Round 15
// baseline (1501.635 us; speedup 1.0000x reference)
//
#include <hip/hip_runtime.h>

// Round 15: break SMEM/DS lgkmcnt mixing in the LDS-consuming FMA loops.
// ds_read completes in-order, s_load out-of-order; both share lgkmcnt, so
// interleaving them forces lgkmcnt(0) drains before each FMA group. Fix:
// stage t/h_new rows into registers first (16xfloat4 in k_update; 8xfloat4
// chunks in k_edge_pab to keep VGPR <= ~64), then pure s_load+FMA stretches.
// Structure otherwise identical to round 14.

#define E 64
#define TWO_E 128

__device__ __forceinline__ void sfma32(float (&acc)[32], float xu, const float* w) {
  #pragma unroll
  for (int i = 0; i < 32; ++i) acc[i] = fmaf(xu, w[i], acc[i]);
}
__device__ __forceinline__ void sfma16(float (&acc)[16], float xu, const float* w) {
  #pragma unroll
  for (int i = 0; i < 16; ++i) acc[i] = fmaf(xu, w[i], acc[i]);
}

// ---------------- zero ----------------
__global__ void k_zero(float4* __restrict__ p, int n4) {
  int i = blockIdx.x * blockDim.x + threadIdx.x;
  if (i < n4) p[i] = make_float4(0.f, 0.f, 0.f, 0.f);
}

// ---------------- counts (per edge / per atom) ----------------
__global__ void k_count_e(const int* __restrict__ rel_e, int* __restrict__ cpos0,
                          int* __restrict__ cpos1, int me) {
  int e = blockIdx.x * blockDim.x + threadIdx.x;
  if (e >= me) return;
  int2 sd = ((const int2*)rel_e)[e];
  atomicAdd(&cpos0[sd.x], 1);
  atomicAdd(&cpos1[sd.y], 1);
}
__global__ void k_count_u(const int* __restrict__ rel_u, int* __restrict__ cnt_u, int mu) {
  int m = blockIdx.x * blockDim.x + threadIdx.x;
  if (m >= mu) return;
  atomicAdd(&cnt_u[rel_u[m]], 1);
}

// ------- multi-block scan, phase 1: per-block sums of cpos0/cpos1 -------
__global__ void __launch_bounds__(256) k_bsum(
    const int* __restrict__ cpos0, const int* __restrict__ cpos1,
    int* __restrict__ bsum, int nn, int nb) {
  __shared__ int l0[256], l1[256];
  int t = threadIdx.x, b = blockIdx.x;
  int i = b * 256 + t;
  l0[t] = (i < nn) ? cpos0[i] : 0;
  l1[t] = (i < nn) ? cpos1[i] : 0;
  __syncthreads();
  for (int off = 128; off > 0; off >>= 1) {
    if (t < off) { l0[t] += l0[t + off]; l1[t] += l1[t + off]; }
    __syncthreads();
  }
  if (t == 0) { bsum[b] = l0[0]; bsum[nb + b] = l1[0]; }
}

// ------- phase 2: exclusive scan of the (<=256) block sums -------
__global__ void __launch_bounds__(256) k_scanblk(
    const int* __restrict__ bsum, int* __restrict__ boff, int nb) {
  __shared__ int l0[256], l1[256];
  int t = threadIdx.x;
  int o0 = (t < nb) ? bsum[t] : 0;
  int o1 = (t < nb) ? bsum[nb + t] : 0;
  l0[t] = o0; l1[t] = o1;
  __syncthreads();
  for (int off = 1; off < 256; off <<= 1) {
    int v0 = (t >= off) ? l0[t - off] : 0;
    int v1 = (t >= off) ? l1[t - off] : 0;
    __syncthreads();
    l0[t] += v0; l1[t] += v1;
    __syncthreads();
  }
  if (t < nb) { boff[t] = l0[t] - o0; boff[nb + t] = l1[t] - o1; }
}

// ------- phase 3: per-block exclusive scan + offsets; writes startp*/cur* ----
__global__ void __launch_bounds__(256) k_wstart(
    const int* __restrict__ cpos0, const int* __restrict__ cpos1,
    const int* __restrict__ boff,
    int* __restrict__ startp, int* __restrict__ startp0, int* __restrict__ startp1,
    int* __restrict__ cur0, int* __restrict__ cur1, int nn, int nb, int me) {
  __shared__ int l0[256], l1[256];
  int t = threadIdx.x, b = blockIdx.x;
  int i = b * 256 + t;
  int c0 = (i < nn) ? cpos0[i] : 0;
  int c1 = (i < nn) ? cpos1[i] : 0;
  l0[t] = c0; l1[t] = c1;
  __syncthreads();
  for (int off = 1; off < 256; off <<= 1) {
    int v0 = (t >= off) ? l0[t - off] : 0;
    int v1 = (t >= off) ? l1[t - off] : 0;
    __syncthreads();
    l0[t] += v0; l1[t] += v1;
    __syncthreads();
  }
  if (i < nn) {
    int s0 = boff[b] + l0[t] - c0;          // exclusive prefix
    int s1 = boff[nb + b] + l1[t] - c1;
    startp0[i] = s0; startp1[i] = s1; startp[i] = s0 + s1;
    cur0[i] = s0; cur1[i] = s1;
  }
  if (i == nn) { startp0[nn] = me; startp1[nn] = me; startp[nn] = 2 * me; }
}

// fill: ord0 (edges sorted by s), pos0 (msgbuf pos of ->s msg), posE1[e] (->d msg)
__global__ void k_fill_e(const int* __restrict__ rel_e,
                         const int* __restrict__ startp, const int* __restrict__ startp0,
                         const int* __restrict__ startp1, const int* __restrict__ cpos0,
                         int* __restrict__ cur0, int* __restrict__ cur1,
                         int* __restrict__ ord0, int* __restrict__ pos0,
                         int* __restrict__ posE1, int me) {
  int e = blockIdx.x * blockDim.x + threadIdx.x;
  if (e >= me) return;
  int2 sd = ((const int2*)rel_e)[e];
  int s = sd.x, d = sd.y;
  int i0 = atomicAdd(&cur0[s], 1);
  ord0[i0] = e;
  pos0[i0] = startp[s] + (i0 - startp0[s]);
  int i1 = atomicAdd(&cur1[d], 1);
  posE1[e] = startp[d] + cpos0[d] + (i1 - startp1[d]);
}

// ------- mu0 = MLP_u(0), me0 = MLP_e(0); also g(layer0) = br for all graphs ----
__global__ void k_mlp0(const float* __restrict__ b1u, const float* __restrict__ W2u,
                       const float* __restrict__ b2u,
                       const float* __restrict__ b1e, const float* __restrict__ W2e,
                       const float* __restrict__ b2e,
                       const float* __restrict__ br,
                       float* __restrict__ mu0, float* __restrict__ me0,
                       float* __restrict__ g, int gn) {
  __shared__ float hu[64], he[128];
  int t = threadIdx.x;                     // 128 threads
  if (t < 64) hu[t] = fmaxf(b1u[t], 0.f);
  he[t] = fmaxf(b1e[t], 0.f);
  __syncthreads();
  if (t < 64) {
    float a = b2u[t];
    for (int k = 0; k < 64; ++k) a = fmaf(hu[k], W2u[k * 64 + t], a);
    mu0[t] = a;
  }
  float a = b2e[t];
  for (int k = 0; k < 128; ++k) a = fmaf(he[k], W2e[k * TWO_E + t], a);
  me0[t] = a;
  if (t < 64) {
    float b = br[t];
    for (int gi = 0; gi < gn; ++gi) g[gi * 64 + t] = b;
  }
}

// ------- layer-0 agg from counts ----------
__global__ void k_agg0(const int* __restrict__ cnt_u, const int* __restrict__ cpos0,
                       const int* __restrict__ cpos1, const float* __restrict__ mu0,
                       const float* __restrict__ me0, float* __restrict__ agg, int nn) {
  int i = blockIdx.x * blockDim.x + threadIdx.x;   // (n, j4)
  int n = i >> 4, j4 = i & 15;
  if (n >= nn) return;
  float cu = (float)cnt_u[n], c0 = (float)cpos0[n], c1 = (float)cpos1[n];
  float4 m = ((const float4*)mu0)[j4];
  float4 a = ((const float4*)me0)[j4];
  float4 b = ((const float4*)(me0 + 64))[j4];
  ((float4*)agg)[i] = make_float4(cu * m.x + c0 * a.x + c1 * b.x,
                                  cu * m.y + c0 * a.y + c1 * b.y,
                                  cu * m.z + c0 * a.z + c1 * b.z,
                                  cu * m.w + c0 * a.w + c1 * b.w);
}

// -------- edge messages, PAB mode, 8 waves / 64 edges; l2 t staged in 8x
// float4 register chunks (pure s_load+FMA stretches between DS batches) -----
__global__ void __launch_bounds__(512) k_edge_pab(
    const int* __restrict__ rel_e, const int* __restrict__ ord0,
    const int* __restrict__ pos0, const int* __restrict__ posE1,
    const float* __restrict__ Pab,
    const float* __restrict__ W2, const float* __restrict__ b2,
    float* __restrict__ msgbuf, int me)
{
  __shared__ __align__(16) float tl[64 * 132];
  const int tid = threadIdx.x;
  const int lane = tid & 63;
  const int wq = __builtin_amdgcn_readfirstlane(tid >> 6);   // 0..7
  const int i = blockIdx.x * 64 + lane;
  const bool valid = (i < me);
  const int ic = valid ? i : (me - 1);
  const int e = ord0[ic];
  const int2 sd = ((const int2*)rel_e)[e];
  const int s = sd.x, d = sd.y;
  const int p_s = pos0[ic];
  const int p_d = posE1[e];

  {
    const float4* pa = (const float4*)(Pab + (size_t)s * 256 + wq * 16);
    const float4* pb = (const float4*)(Pab + (size_t)d * 256 + 128 + wq * 16);
    float4* trow = (float4*)&tl[lane * 132 + wq * 16];
    #pragma unroll
    for (int u = 0; u < 4; ++u) {
      float4 va = pa[u], vb = pb[u];
      trow[u] = make_float4(fmaxf(va.x + vb.x, 0.f), fmaxf(va.y + vb.y, 0.f),
                            fmaxf(va.z + vb.z, 0.f), fmaxf(va.w + vb.w, 0.f));
    }
  }
  __syncthreads();

  float o[16];
  {
    const float* bp = b2 + wq * 16;
    #pragma unroll
    for (int u = 0; u < 16; ++u) o[u] = bp[u];
  }
  {
    const float4* tr = (const float4*)&tl[lane * 132];
    const float* w = W2 + wq * 16;          // row stride TWO_E, 128 rows
    #pragma unroll 1
    for (int c = 0; c < 4; ++c) {           // 4 chunks x 8 float4 (32 rows each)
      float4 r0 = tr[c*8+0], r1 = tr[c*8+1], r2 = tr[c*8+2], r3 = tr[c*8+3];
      float4 r4 = tr[c*8+4], r5 = tr[c*8+5], r6 = tr[c*8+6], r7 = tr[c*8+7];
      sfma16(o, r0.x, w);            sfma16(o, r0.y, w + TWO_E);
      sfma16(o, r0.z, w + 2*TWO_E);  sfma16(o, r0.w, w + 3*TWO_E);  w += 4*TWO_E;
      sfma16(o, r1.x, w);            sfma16(o, r1.y, w + TWO_E);
      sfma16(o, r1.z, w + 2*TWO_E);  sfma16(o, r1.w, w + 3*TWO_E);  w += 4*TWO_E;
      sfma16(o, r2.x, w);            sfma16(o, r2.y, w + TWO_E);
      sfma16(o, r2.z, w + 2*TWO_E);  sfma16(o, r2.w, w + 3*TWO_E);  w += 4*TWO_E;
      sfma16(o, r3.x, w);            sfma16(o, r3.y, w + TWO_E);
      sfma16(o, r3.z, w + 2*TWO_E);  sfma16(o, r3.w, w + 3*TWO_E);  w += 4*TWO_E;
      sfma16(o, r4.x, w);            sfma16(o, r4.y, w + TWO_E);
      sfma16(o, r4.z, w + 2*TWO_E);  sfma16(o, r4.w, w + 3*TWO_E);  w += 4*TWO_E;
      sfma16(o, r5.x, w);            sfma16(o, r5.y, w + TWO_E);
      sfma16(o, r5.z, w + 2*TWO_E);  sfma16(o, r5.w, w + 3*TWO_E);  w += 4*TWO_E;
      sfma16(o, r6.x, w);            sfma16(o, r6.y, w + TWO_E);
      sfma16(o, r6.z, w + 2*TWO_E);  sfma16(o, r6.w, w + 3*TWO_E);  w += 4*TWO_E;
      sfma16(o, r7.x, w);            sfma16(o, r7.y, w + TWO_E);
      sfma16(o, r7.z, w + 2*TWO_E);  sfma16(o, r7.w, w + 3*TWO_E);  w += 4*TWO_E;
    }
  }
  if (valid) {
    int p0 = (wq >= 4) ? p_d : p_s;
    float4* mp = (float4*)(msgbuf + (size_t)p0 * E + (wq & 3) * 16);
    #pragma unroll
    for (int u = 0; u < 4; ++u)
      mp[u] = make_float4(o[4*u], o[4*u+1], o[4*u+2], o[4*u+3]);
  }
}

// -------- edge messages, fallback (reads h; used only if ws too small) ------
__global__ void __launch_bounds__(256) k_edge_fb(
    const int* __restrict__ rel_e, const int* __restrict__ ord0,
    const int* __restrict__ pos0, const int* __restrict__ posE1,
    const float* __restrict__ h,
    const float* __restrict__ W1, const float* __restrict__ b1,
    const float* __restrict__ W2, const float* __restrict__ b2,
    float* __restrict__ msgbuf, int me)
{
  __shared__ __align__(16) float tl[64 * 132];
  const int tid = threadIdx.x;
  const int lane = tid & 63;
  const int wq = __builtin_amdgcn_readfirstlane(tid >> 6);
  const int i = blockIdx.x * 64 + lane;
  const bool valid = (i < me);
  const int ic = valid ? i : (me - 1);
  const int e = ord0[ic];
  const int2 sd = ((const int2*)rel_e)[e];
  const int s = sd.x, d = sd.y;
  const int p_s = pos0[ic];
  const int p_d = posE1[e];
  const float4* xs4 = (const float4*)(h + (size_t)s * E);
  const float4* xd4 = (const float4*)(h + (size_t)d * E);

  float acc[32];
  {
    const float* bp = b1 + wq * 32;
    #pragma unroll
    for (int u = 0; u < 32; ++u) acc[u] = bp[u];
  }
  {
    const float* w = W1 + wq * 32;
    #pragma unroll 2
    for (int k4 = 0; k4 < 16; ++k4) {
      float4 xv = xs4[k4];
      sfma32(acc, xv.x, w);
      sfma32(acc, xv.y, w + TWO_E);
      sfma32(acc, xv.z, w + 2 * TWO_E);
      sfma32(acc, xv.w, w + 3 * TWO_E);
      w += 4 * TWO_E;
    }
    #pragma unroll 2
    for (int k4 = 0; k4 < 16; ++k4) {
      float4 xv = xd4[k4];
      sfma32(acc, xv.x, w);
      sfma32(acc, xv.y, w + TWO_E);
      sfma32(acc, xv.z, w + 2 * TWO_E);
      sfma32(acc, xv.w, w + 3 * TWO_E);
      w += 4 * TWO_E;
    }
  }
  {
    float4* trow = (float4*)&tl[lane * 132 + wq * 32];
    #pragma unroll
    for (int u = 0; u < 8; ++u)
      trow[u] = make_float4(fmaxf(acc[4*u], 0.f), fmaxf(acc[4*u+1], 0.f),
                            fmaxf(acc[4*u+2], 0.f), fmaxf(acc[4*u+3], 0.f));
  }
  __syncthreads();

  float o[32];
  {
    const float* bp = b2 + wq * 32;
    #pragma unroll
    for (int u = 0; u < 32; ++u) o[u] = bp[u];
  }
  {
    const float4* tr = (const float4*)&tl[lane * 132];
    const float* w = W2 + wq * 32;
    #pragma unroll 4
    for (int kk = 0; kk < 32; ++kk) {
      float4 tv = tr[kk];
      sfma32(o, tv.x, w);
      sfma32(o, tv.y, w + TWO_E);
      sfma32(o, tv.z, w + 2 * TWO_E);
      sfma32(o, tv.w, w + 3 * TWO_E);
      w += 4 * TWO_E;
    }
  }
  if (valid) {
    int p0 = (wq >> 1) ? p_d : p_s;
    float4* mp = (float4*)(msgbuf + (size_t)p0 * E + (wq & 1) * 32);
    #pragma unroll
    for (int u = 0; u < 8; ++u)
      mp[u] = make_float4(o[4*u], o[4*u+1], o[4*u+2], o[4*u+3]);
  }
}

// ------- gather: agg[n] += streaming sum of msgbuf[startp[n]..startp[n+1]) ----
__global__ void __launch_bounds__(256) k_gather(
    const float* __restrict__ msgbuf, const int* __restrict__ startp,
    float* __restrict__ agg, int nn)
{
  int wave = threadIdx.x >> 6;
  int j = threadIdx.x & 63;
  int n = blockIdx.x * 4 + wave;
  if (n >= nn) return;
  int s0 = startp[n], s1 = startp[n + 1];
  int cnt = s1 - s0;
  const float* p = msgbuf + (size_t)s0 * E + j;
  float v0 = 0.f, v1 = 0.f;
  int i = 0;
  for (; i + 1 < cnt; i += 2) { v0 += p[0]; v1 += p[E]; p += 2 * E; }
  if (i < cnt) v0 += p[0];
  agg[(size_t)n * E + j] += v0 + v1;
}

// ------- fused readout+proj: one block per graph (contiguous node runs) ----
__global__ void __launch_bounds__(256) k_readout_g(
    const float* __restrict__ h, const int* __restrict__ gids,
    const float* __restrict__ Wr, const float* __restrict__ br,
    float* __restrict__ g, int nn, int npg)
{
  __shared__ float ls[4][64];
  __shared__ float grow[64];
  const int j = threadIdx.x & 63;
  const int w = threadIdx.x >> 6;
  const int base = blockIdx.x * npg;
  float acc = 0.f;
  for (int i = w; i < npg; i += 4) {
    int node = base + i;
    if (node < nn) acc += h[(size_t)node * 64 + j];
  }
  ls[w][j] = acc;
  __syncthreads();
  if (w == 0) grow[j] = ls[0][j] + ls[1][j] + ls[2][j] + ls[3][j];
  __syncthreads();
  float p = 0.f;
  #pragma unroll
  for (int kk = 0; kk < 16; ++kk) {
    int k = w * 16 + kk;
    p = fmaf(grow[k], Wr[k * 64 + j], p);
  }
  ls[w][j] = p;
  __syncthreads();
  if (w == 0) {
    int gout = gids[base];
    g[gout * 64 + j] = ls[0][j] + ls[1][j] + ls[2][j] + ls[3][j] + br[j];
  }
}

// -------- node update (4-wave): wave q owns dims q*16..+16. LDS rows staged
// into full register copies before each FMA phase (no DS/SMEM interleave).
template <bool DO_NEXT>
__global__ void __launch_bounds__(256) k_update(
    float* __restrict__ h, float* __restrict__ agg,
    const float* __restrict__ gvec, const int* __restrict__ gids,
    const float* __restrict__ Wu1, const float* __restrict__ bu1,
    const float* __restrict__ Wu2, const float* __restrict__ bu2,
    const float* __restrict__ Wg1, const float* __restrict__ bg1,
    const float* __restrict__ Wg2, const float* __restrict__ bg2,
    const float* __restrict__ lnw, const float* __restrict__ lnb,
    const int* __restrict__ cnt_u,
    const float* __restrict__ Wmu1, const float* __restrict__ bmu1,
    const float* __restrict__ Wmu2, const float* __restrict__ bmu2,
    const float* __restrict__ W1e, const float* __restrict__ b1e,
    float* __restrict__ Pab, int do_pab, int nn)
{
  __shared__ __align__(16) float tl[64 * 68];    // 17,408 B
  __shared__ float st[64 * 9];                   // 2,304 B
  const int tid = threadIdx.x;
  const int lane = tid & 63;
  const int q = __builtin_amdgcn_readfirstlane(tid >> 6);  // 0..3, dim quarter
  const int n = blockIdx.x * 64 + lane;
  const bool valid = (n < nn);
  const int ncl = valid ? n : (nn - 1);
  const int gid = gids[ncl];
  const float4* hx = (const float4*)(h + (size_t)ncl * E);
  const float4* ax = (const float4*)(agg + (size_t)ncl * E);
  const float4* gx = (const float4*)(gvec + (size_t)gid * E);

  float res[16];

  #pragma unroll
  for (int pass = 0; pass < 2; ++pass) {
    const float* W1 = (pass == 0) ? Wu1 : Wg1;
    const float* B1 = (pass == 0) ? bu1 : bg1;
    const float* W2 = (pass == 0) ? Wu2 : Wg2;
    const float* B2 = (pass == 0) ? bu2 : bg2;
    const float4* xb = (pass == 0) ? ax : gx;

    // layer 1: hidden quarter q from 128-wide [h, xb]  (global loads: vmcnt)
    float acc[16];
    {
      const float* bp = B1 + q * 16;
      #pragma unroll
      for (int u = 0; u < 16; ++u) acc[u] = bp[u];
    }
    {
      const float* w = W1 + q * 16;        // row stride E (out dim 64)
      #pragma unroll 2
      for (int k4 = 0; k4 < 16; ++k4) {
        float4 xv = hx[k4];
        sfma16(acc, xv.x, w);
        sfma16(acc, xv.y, w + E);
        sfma16(acc, xv.z, w + 2 * E);
        sfma16(acc, xv.w, w + 3 * E);
        w += 4 * E;
      }
      #pragma unroll 2
      for (int k4 = 0; k4 < 16; ++k4) {
        float4 xv = xb[k4];
        sfma16(acc, xv.x, w);
        sfma16(acc, xv.y, w + E);
        sfma16(acc, xv.z, w + 2 * E);
        sfma16(acc, xv.w, w + 3 * E);
        w += 4 * E;
      }
    }
    {
      float4* trow = (float4*)&tl[lane * 68 + q * 16];
      #pragma unroll
      for (int u = 0; u < 4; ++u)
        trow[u] = make_float4(fmaxf(acc[4*u], 0.f), fmaxf(acc[4*u+1], 0.f),
                              fmaxf(acc[4*u+2], 0.f), fmaxf(acc[4*u+3], 0.f));
    }
    __syncthreads();

    // layer 2: stage full t row -> regs, then pure s_load+FMA
    float4 tr_r[16];
    {
      const float4* tr = (const float4*)&tl[lane * 68];
      #pragma unroll
      for (int u = 0; u < 16; ++u) tr_r[u] = tr[u];
    }
    float o[16];
    {
      const float* bp = B2 + q * 16;
      #pragma unroll
      for (int u = 0; u < 16; ++u) o[u] = bp[u];
    }
    {
      const float* w = W2 + q * 16;
      #pragma unroll
      for (int kk = 0; kk < 16; ++kk) {
        float4 tv = tr_r[kk];
        sfma16(o, tv.x, w);
        sfma16(o, tv.y, w + E);
        sfma16(o, tv.z, w + 2 * E);
        sfma16(o, tv.w, w + 3 * E);
        w += 4 * E;
      }
    }

    // LayerNorm across 4 waves (two-pass, matches reference form)
    float s1 = 0.f;
    #pragma unroll
    for (int u = 0; u < 16; ++u) s1 += o[u];
    st[lane * 9 + q] = s1;
    __syncthreads();
    float mu = (st[lane * 9 + 0] + st[lane * 9 + 1] +
                st[lane * 9 + 2] + st[lane * 9 + 3]) * (1.f / E);
    float s2 = 0.f;
    #pragma unroll
    for (int u = 0; u < 16; ++u) { float dm = o[u] - mu; s2 += dm * dm; }
    st[lane * 9 + 4 + q] = s2;
    __syncthreads();
    float var = (st[lane * 9 + 4] + st[lane * 9 + 5] +
                 st[lane * 9 + 6] + st[lane * 9 + 7]) * (1.f / E);
    float rs = rsqrtf(var + 1e-5f);
    {
      const float* lw = lnw + q * 16;
      const float* lb = lnb + q * 16;
      #pragma unroll
      for (int u = 0; u < 16; ++u) {
        float v = (o[u] - mu) * rs * lw[u] + lb[u];
        if (pass == 0) res[u] = v; else res[u] += v;
      }
    }
  }

  // ---- residual: h_new = h + res (quarter q) ----
  float hnew[16];
  {
    const float4* hr = (const float4*)(h + (size_t)ncl * E + q * 16);
    #pragma unroll
    for (int u = 0; u < 4; ++u) {
      float4 hv = hr[u];
      hnew[4*u+0] = hv.x + res[4*u+0];
      hnew[4*u+1] = hv.y + res[4*u+1];
      hnew[4*u+2] = hv.z + res[4*u+2];
      hnew[4*u+3] = hv.w + res[4*u+3];
    }
  }
  if (valid) {
    float4* hw = (float4*)(h + (size_t)n * E + q * 16);
    #pragma unroll
    for (int u = 0; u < 4; ++u)
      hw[u] = make_float4(hnew[4*u], hnew[4*u+1], hnew[4*u+2], hnew[4*u+3]);
  }

  if (DO_NEXT) {
    // stage h_new row in LDS (LN barriers ordered all prior tl reads)
    {
      float4* trow = (float4*)&tl[lane * 68 + q * 16];
      #pragma unroll
      for (int u = 0; u < 4; ++u)
        trow[u] = make_float4(hnew[4*u], hnew[4*u+1], hnew[4*u+2], hnew[4*u+3]);
    }
    __syncthreads();

    // stage full h_new row -> regs once; reused by unary-l1 AND pab
    float4 hr_r[16];
    {
      const float4* tr = (const float4*)&tl[lane * 68];
      #pragma unroll
      for (int u = 0; u < 16; ++u) hr_r[u] = tr[u];
    }

    // unary layer 1: hidden quarter q over full 64-wide h_new (regs)
    float acc[16];
    {
      const float* bp = bmu1 + q * 16;
      #pragma unroll
      for (int u = 0; u < 16; ++u) acc[u] = bp[u];
    }
    {
      const float* w = Wmu1 + q * 16;
      #pragma unroll
      for (int kk = 0; kk < 16; ++kk) {
        float4 tv = hr_r[kk];
        sfma16(acc, tv.x, w);
        sfma16(acc, tv.y, w + E);
        sfma16(acc, tv.z, w + 2 * E);
        sfma16(acc, tv.w, w + 3 * E);
        w += 4 * E;
      }
    }

    // PAB from h_new (regs): wave q owns cols q*64..q*64+64, two 32-col chunks
    if (do_pab) {
      #pragma unroll 1
      for (int c = 0; c < 2; ++c) {
        const int col = q * 64 + c * 32;          // uniform
        const int rbase = (col < 128) ? 0 : 64;
        const int cw = (col < 128) ? col : (col - 128);
        float pacc[32];
        if (col < 128) {
          const float* bp = b1e + cw;
          #pragma unroll
          for (int u = 0; u < 32; ++u) pacc[u] = bp[u];
        } else {
          #pragma unroll
          for (int u = 0; u < 32; ++u) pacc[u] = 0.f;
        }
        const float* w = W1e + rbase * TWO_E + cw;
        #pragma unroll
        for (int kk = 0; kk < 16; ++kk) {
          float4 tv = hr_r[kk];
          sfma32(pacc, tv.x, w);
          sfma32(pacc, tv.y, w + TWO_E);
          sfma32(pacc, tv.z, w + 2 * TWO_E);
          sfma32(pacc, tv.w, w + 3 * TWO_E);
          w += 4 * TWO_E;
        }
        if (valid) {
          float4* op = (float4*)(Pab + (size_t)n * 256 + col);
          #pragma unroll
          for (int u = 0; u < 8; ++u)
            op[u] = make_float4(pacc[4*u], pacc[4*u+1], pacc[4*u+2], pacc[4*u+3]);
        }
      }
    }
    __syncthreads();        // all reads of h_new LDS done before overwrite
    {
      float4* trow = (float4*)&tl[lane * 68 + q * 16];
      #pragma unroll
      for (int u = 0; u < 4; ++u)
        trow[u] = make_float4(fmaxf(acc[4*u], 0.f), fmaxf(acc[4*u+1], 0.f),
                              fmaxf(acc[4*u+2], 0.f), fmaxf(acc[4*u+3], 0.f));
    }
    __syncthreads();

    // unary layer 2: stage hidden row -> regs, then pure s_load+FMA
    float4 ur_r[16];
    {
      const float4* tr = (const float4*)&tl[lane * 68];
      #pragma unroll
      for (int u = 0; u < 16; ++u) ur_r[u] = tr[u];
    }
    float o[16];
    {
      const float* bp = bmu2 + q * 16;
      #pragma unroll
      for (int u = 0; u < 16; ++u) o[u] = bp[u];
    }
    {
      const float* w = Wmu2 + q * 16;
      #pragma unroll
      for (int kk = 0; kk < 16; ++kk) {
        float4 tv = ur_r[kk];
        sfma16(o, tv.x, w);
        sfma16(o, tv.y, w + E);
        sfma16(o, tv.z, w + 2 * E);
        sfma16(o, tv.w, w + 3 * E);
        w += 4 * E;
      }
    }
    if (valid) {
      float cf = (float)cnt_u[n];
      float4* ap = (float4*)(agg + (size_t)n * E + q * 16);
      #pragma unroll
      for (int u = 0; u < 4; ++u)
        ap[u] = make_float4(o[4*u] * cf, o[4*u+1] * cf, o[4*u+2] * cf, o[4*u+3] * cf);
    }
  }
}

extern "C" void kernel_launch(void* const* d_in, const int* in_sizes, int n_in,
                              void* d_out, int out_size, void* d_ws, size_t ws_size,
                              hipStream_t stream) {
  (void)n_in; (void)out_size;
  const int*   rel_u = (const int*)d_in[0];
  const int*   rel_e = (const int*)d_in[1];
  const int*   gids  = (const int*)d_in[2];
  const float* Wm1_u = (const float*)d_in[4];
  const float* bm1_u = (const float*)d_in[5];
  const float* Wm2_u = (const float*)d_in[6];
  const float* bm2_u = (const float*)d_in[7];
  const float* Wm1_e = (const float*)d_in[8];
  const float* bm1_e = (const float*)d_in[9];
  const float* Wm2_e = (const float*)d_in[10];
  const float* bm2_e = (const float*)d_in[11];
  const float* Wu1   = (const float*)d_in[12];
  const float* bu1   = (const float*)d_in[13];
  const float* Wu2   = (const float*)d_in[14];
  const float* bu2   = (const float*)d_in[15];
  const float* lnw   = (const float*)d_in[16];
  const float* lnb   = (const float*)d_in[17];
  const float* Wr    = (const float*)d_in[18];
  const float* br    = (const float*)d_in[19];
  const float* Wg1   = (const float*)d_in[20];
  const float* bg1   = (const float*)d_in[21];
  const float* Wg2   = (const float*)d_in[22];
  const float* bg2   = (const float*)d_in[23];

  const int MU_ = in_sizes[0];          // 100000
  const int ME_ = in_sizes[1] / 2;      // 200000
  const int NN  = in_sizes[2];          // 50000
  const int GN  = 100;
  const int NPG = NN / GN;              // 500 nodes per graph (contiguous)
  const int M2  = 2 * ME_;              // 400000 edge message slots
  const int NB  = (NN + 255) / 256;     // scan blocks (196 <= 256)
  const int NBW = (NN + 256) / 256;     // k_wstart covers i = 0..NN
  const int NBU = (NN + 63) / 64;       // k_update blocks (782)

  // ---- workspace layout ----
  float* h       = (float*)d_out;
  float* agg     = (float*)d_ws;                           // [N*64]
  float* g       = agg + (size_t)NN * E;                   // [G*64]
  float* mu0     = g + (size_t)GN * E;                     // [64]
  float* me0     = mu0 + 64;                               // [128]
  float* msgbuf  = me0 + TWO_E;                            // [M2*64]
  int*   cpos0   = (int*)(msgbuf + (size_t)M2 * E);        // [N]
  int*   cpos1   = cpos0 + NN;                             // [N]
  int*   cnt_u   = cpos1 + NN;                             // [N]
  int*   startp  = cnt_u + NN;                             // [N+1]
  int*   startp0 = startp + NN + 1;                        // [N+1]
  int*   startp1 = startp0 + NN + 1;                       // [N+1]
  int*   cur0    = startp1 + NN + 1;                       // [N+1]
  int*   cur1    = cur0 + NN + 1;                          // [N+1]
  int*   ord0    = cur1 + NN + 1;                          // [ME]
  int*   pos0    = ord0 + ME_;                             // [ME]
  int*   posE1   = pos0 + ME_;                             // [ME]
  int*   bsum    = posE1 + ME_;                            // [2*NB]
  int*   boff    = bsum + 2 * NB;                          // [2*NB]
  size_t int_end = (size_t)(boff + 2 * NB - (int*)d_ws);
  size_t pab_off = (int_end + 3) & ~(size_t)3;
  float* Pab     = (float*)d_ws + pab_off;                 // [N*256]
  size_t need_pab = (pab_off + (size_t)NN * 256) * 4;
  const bool pab_mode = (ws_size >= need_pab);

  { // h = 0
    int n4 = NN * E / 4;
    k_zero<<<(n4 + 255) / 256, 256, 0, stream>>>((float4*)h, n4);
  }
  { // zero [cpos0, cpos1, cnt_u] (3N ints; small spill into startp is ok)
    int n4 = (3 * NN + 4) / 4;
    k_zero<<<(n4 + 255) / 256, 256, 0, stream>>>((float4*)cpos0, n4);
  }
  // ---- CSR + counts + constant messages (once; graph static) ----
  k_count_e<<<(ME_ + 255) / 256, 256, 0, stream>>>(rel_e, cpos0, cpos1, ME_);
  k_count_u<<<(MU_ + 255) / 256, 256, 0, stream>>>(rel_u, cnt_u, MU_);
  k_bsum<<<NB, 256, 0, stream>>>(cpos0, cpos1, bsum, NN, NB);
  k_scanblk<<<1, 256, 0, stream>>>(bsum, boff, NB);
  k_wstart<<<NBW, 256, 0, stream>>>(cpos0, cpos1, boff, startp, startp0, startp1,
                                    cur0, cur1, NN, NB, ME_);
  k_fill_e<<<(ME_ + 255) / 256, 256, 0, stream>>>(
      rel_e, startp, startp0, startp1, cpos0, cur0, cur1, ord0, pos0, posE1, ME_);
  k_mlp0<<<1, 128, 0, stream>>>(bm1_u, Wm2_u, bm2_u, bm1_e, Wm2_e, bm2_e,
                                br, mu0, me0, g, GN);

  // ---- layer 0: messages constant; g = br; update emits unary agg + Pab ----
  k_agg0<<<(NN * 16 + 255) / 256, 256, 0, stream>>>(cnt_u, cpos0, cpos1, mu0, me0, agg, NN);
  k_update<true><<<NBU, 256, 0, stream>>>(
      h, agg, g, gids, Wu1, bu1, Wu2, bu2, Wg1, bg1, Wg2, bg2, lnw, lnb,
      cnt_u, Wm1_u, bm1_u, Wm2_u, bm2_u, Wm1_e, bm1_e, Pab, pab_mode ? 1 : 0, NN);

  // ---- layers 1..3 ----
  for (int l = 1; l < 4; ++l) {
    if (pab_mode)
      k_edge_pab<<<(ME_ + 63) / 64, 512, 0, stream>>>(
          rel_e, ord0, pos0, posE1, Pab, Wm2_e, bm2_e, msgbuf, ME_);
    else
      k_edge_fb<<<(ME_ + 63) / 64, 256, 0, stream>>>(
          rel_e, ord0, pos0, posE1, h, Wm1_e, bm1_e, Wm2_e, bm2_e, msgbuf, ME_);
    k_gather<<<(NN + 3) / 4, 256, 0, stream>>>(msgbuf, startp, agg, NN);
    k_readout_g<<<GN, 256, 0, stream>>>(h, gids, Wr, br, g, NN, NPG);
    if (l < 3)
      k_update<true><<<NBU, 256, 0, stream>>>(
          h, agg, g, gids, Wu1, bu1, Wu2, bu2, Wg1, bg1, Wg2, bg2, lnw, lnb,
          cnt_u, Wm1_u, bm1_u, Wm2_u, bm2_u, Wm1_e, bm1_e, Pab, pab_mode ? 1 : 0, NN);
    else
      k_update<false><<<NBU, 256, 0, stream>>>(
          h, agg, g, gids, Wu1, bu1, Wu2, bu2, Wg1, bg1, Wg2, bg2, lnw, lnb,
          cnt_u, Wm1_u, bm1_u, Wm2_u, bm2_u, Wm1_e, bm1_e, Pab, 0, NN);
  }
}

// Round 16
// 837.059 us; speedup vs baseline: 1.7939x; 1.7939x over previous
//
#include <hip/hip_runtime.h>

// Round 16: revert to the round-14 configuration (measured 839 us) after the
// round-15 register-staging experiment regressed (VGPR 40->132, occupancy
// 28->9%, k_update 105->340 us). This is the validated best variant:
//  - k_edge_pab: 8 waves / 64 edges, sorted traversal, CSR-position writes.
//  - k_update: 4 waves / 64 nodes, fused unary-msg + Pab epilogue.
//  - parallel 3-phase scan, fused readout, layer-0 constant folding.

#define E 64
#define TWO_E 128

__device__ __forceinline__ void sfma32(float (&acc)[32], float xu, const float* w) {
  #pragma unroll
  for (int i = 0; i < 32; ++i) acc[i] = fmaf(xu, w[i], acc[i]);
}
__device__ __forceinline__ void sfma16(float (&acc)[16], float xu, const float* w) {
  #pragma unroll
  for (int i = 0; i < 16; ++i) acc[i] = fmaf(xu, w[i], acc[i]);
}

// ---------------- zero ----------------
__global__ void k_zero(float4* __restrict__ p, int n4) {
  int i = blockIdx.x * blockDim.x + threadIdx.x;
  if (i < n4) p[i] = make_float4(0.f, 0.f, 0.f, 0.f);
}

// ---------------- counts (per edge / per atom) ----------------
__global__ void k_count_e(const int* __restrict__ rel_e, int* __restrict__ cpos0,
                          int* __restrict__ cpos1, int me) {
  int e = blockIdx.x * blockDim.x + threadIdx.x;
  if (e >= me) return;
  int2 sd = ((const int2*)rel_e)[e];
  atomicAdd(&cpos0[sd.x], 1);
  atomicAdd(&cpos1[sd.y], 1);
}
__global__ void k_count_u(const int* __restrict__ rel_u, int* __restrict__ cnt_u, int mu) {
  int m = blockIdx.x * blockDim.x + threadIdx.x;
  if (m >= mu) return;
  atomicAdd(&cnt_u[rel_u[m]], 1);
}

// ------- multi-block scan, phase 1: per-block sums of cpos0/cpos1 -------
__global__ void __launch_bounds__(256) k_bsum(
    const int* __restrict__ cpos0, const int* __restrict__ cpos1,
    int* __restrict__ bsum, int nn, int nb) {
  __shared__ int l0[256], l1[256];
  int t = threadIdx.x, b = blockIdx.x;
  int i = b * 256 + t;
  l0[t] = (i < nn) ? cpos0[i] : 0;
  l1[t] = (i < nn) ? cpos1[i] : 0;
  __syncthreads();
  for (int off = 128; off > 0; off >>= 1) {
    if (t < off) { l0[t] += l0[t + off]; l1[t] += l1[t + off]; }
    __syncthreads();
  }
  if (t == 0) { bsum[b] = l0[0]; bsum[nb + b] = l1[0]; }
}

// ------- phase 2: exclusive scan of the (<=256) block sums -------
__global__ void __launch_bounds__(256) k_scanblk(
    const int* __restrict__ bsum, int* __restrict__ boff, int nb) {
  __shared__ int l0[256], l1[256];
  int t = threadIdx.x;
  int o0 = (t < nb) ? bsum[t] : 0;
  int o1 = (t < nb) ? bsum[nb + t] : 0;
  l0[t] = o0; l1[t] = o1;
  __syncthreads();
  for (int off = 1; off < 256; off <<= 1) {
    int v0 = (t >= off) ? l0[t - off] : 0;
    int v1 = (t >= off) ? l1[t - off] : 0;
    __syncthreads();
    l0[t] += v0; l1[t] += v1;
    __syncthreads();
  }
  if (t < nb) { boff[t] = l0[t] - o0; boff[nb + t] = l1[t] - o1; }
}

// ------- phase 3: per-block exclusive scan + offsets; writes startp*/cur* ----
__global__ void __launch_bounds__(256) k_wstart(
    const int* __restrict__ cpos0, const int* __restrict__ cpos1,
    const int* __restrict__ boff,
    int* __restrict__ startp, int* __restrict__ startp0, int* __restrict__ startp1,
    int* __restrict__ cur0, int* __restrict__ cur1, int nn, int nb, int me) {
  __shared__ int l0[256], l1[256];
  int t = threadIdx.x, b = blockIdx.x;
  int i = b * 256 + t;
  int c0 = (i < nn) ? cpos0[i] : 0;
  int c1 = (i < nn) ? cpos1[i] : 0;
  l0[t] = c0; l1[t] = c1;
  __syncthreads();
  for (int off = 1; off < 256; off <<= 1) {
    int v0 = (t >= off) ? l0[t - off] : 0;
    int v1 = (t >= off) ? l1[t - off] : 0;
    __syncthreads();
    l0[t] += v0; l1[t] += v1;
    __syncthreads();
  }
  if (i < nn) {
    int s0 = boff[b] + l0[t] - c0;          // exclusive prefix
    int s1 = boff[nb + b] + l1[t] - c1;
    startp0[i] = s0; startp1[i] = s1; startp[i] = s0 + s1;
    cur0[i] = s0; cur1[i] = s1;
  }
  if (i == nn) { startp0[nn] = me; startp1[nn] = me; startp[nn] = 2 * me; }
}

// fill: ord0 (edges sorted by s), pos0 (msgbuf pos of ->s msg), posE1[e] (->d msg)
__global__ void k_fill_e(const int* __restrict__ rel_e,
                         const int* __restrict__ startp, const int* __restrict__ startp0,
                         const int* __restrict__ startp1, const int* __restrict__ cpos0,
                         int* __restrict__ cur0, int* __restrict__ cur1,
                         int* __restrict__ ord0, int* __restrict__ pos0,
                         int* __restrict__ posE1, int me) {
  int e = blockIdx.x * blockDim.x + threadIdx.x;
  if (e >= me) return;
  int2 sd = ((const int2*)rel_e)[e];
  int s = sd.x, d = sd.y;
  int i0 = atomicAdd(&cur0[s], 1);
  ord0[i0] = e;
  pos0[i0] = startp[s] + (i0 - startp0[s]);
  int i1 = atomicAdd(&cur1[d], 1);
  posE1[e] = startp[d] + cpos0[d] + (i1 - startp1[d]);
}

// ------- mu0 = MLP_u(0), me0 = MLP_e(0); also g(layer0) = br for all graphs ----
__global__ void k_mlp0(const float* __restrict__ b1u, const float* __restrict__ W2u,
                       const float* __restrict__ b2u,
                       const float* __restrict__ b1e, const float* __restrict__ W2e,
                       const float* __restrict__ b2e,
                       const float* __restrict__ br,
                       float* __restrict__ mu0, float* __restrict__ me0,
                       float* __restrict__ g, int gn) {
  __shared__ float hu[64], he[128];
  int t = threadIdx.x;                     // 128 threads
  if (t < 64) hu[t] = fmaxf(b1u[t], 0.f);
  he[t] = fmaxf(b1e[t], 0.f);
  __syncthreads();
  if (t < 64) {
    float a = b2u[t];
    for (int k = 0; k < 64; ++k) a = fmaf(hu[k], W2u[k * 64 + t], a);
    mu0[t] = a;
  }
  float a = b2e[t];
  for (int k = 0; k < 128; ++k) a = fmaf(he[k], W2e[k * TWO_E + t], a);
  me0[t] = a;
  if (t < 64) {
    float b = br[t];
    for (int gi = 0; gi < gn; ++gi) g[gi * 64 + t] = b;
  }
}

// ------- layer-0 agg from counts ----------
__global__ void k_agg0(const int* __restrict__ cnt_u, const int* __restrict__ cpos0,
                       const int* __restrict__ cpos1, const float* __restrict__ mu0,
                       const float* __restrict__ me0, float* __restrict__ agg, int nn) {
  int i = blockIdx.x * blockDim.x + threadIdx.x;   // (n, j4)
  int n = i >> 4, j4 = i & 15;
  if (n >= nn) return;
  float cu = (float)cnt_u[n], c0 = (float)cpos0[n], c1 = (float)cpos1[n];
  float4 m = ((const float4*)mu0)[j4];
  float4 a = ((const float4*)me0)[j4];
  float4 b = ((const float4*)(me0 + 64))[j4];
  ((float4*)agg)[i] = make_float4(cu * m.x + c0 * a.x + c1 * b.x,
                                  cu * m.y + c0 * a.y + c1 * b.y,
                                  cu * m.z + c0 * a.z + c1 * b.z,
                                  cu * m.w + c0 * a.w + c1 * b.w);
}

// -------- edge messages, PAB mode, 8 waves / 64 edges --------
__global__ void __launch_bounds__(512) k_edge_pab(
    const int* __restrict__ rel_e, const int* __restrict__ ord0,
    const int* __restrict__ pos0, const int* __restrict__ posE1,
    const float* __restrict__ Pab,
    const float* __restrict__ W2, const float* __restrict__ b2,
    float* __restrict__ msgbuf, int me)
{
  __shared__ __align__(16) float tl[64 * 132];
  const int tid = threadIdx.x;
  const int lane = tid & 63;
  const int wq = __builtin_amdgcn_readfirstlane(tid >> 6);   // 0..7
  const int i = blockIdx.x * 64 + lane;
  const bool valid = (i < me);
  const int ic = valid ? i : (me - 1);
  const int e = ord0[ic];
  const int2 sd = ((const int2*)rel_e)[e];
  const int s = sd.x, d = sd.y;
  const int p_s = pos0[ic];
  const int p_d = posE1[e];

  {
    const float4* pa = (const float4*)(Pab + (size_t)s * 256 + wq * 16);
    const float4* pb = (const float4*)(Pab + (size_t)d * 256 + 128 + wq * 16);
    float4* trow = (float4*)&tl[lane * 132 + wq * 16];
    #pragma unroll
    for (int u = 0; u < 4; ++u) {
      float4 va = pa[u], vb = pb[u];
      trow[u] = make_float4(fmaxf(va.x + vb.x, 0.f), fmaxf(va.y + vb.y, 0.f),
                            fmaxf(va.z + vb.z, 0.f), fmaxf(va.w + vb.w, 0.f));
    }
  }
  __syncthreads();

  float o[16];
  {
    const float* bp = b2 + wq * 16;
    #pragma unroll
    for (int u = 0; u < 16; ++u) o[u] = bp[u];
  }
  {
    const float4* tr = (const float4*)&tl[lane * 132];
    const float* w = W2 + wq * 16;          // row stride TWO_E, 128 rows
    #pragma unroll 4
    for (int kk = 0; kk < 32; ++kk) {
      float4 tv = tr[kk];
      sfma16(o, tv.x, w);
      sfma16(o, tv.y, w + TWO_E);
      sfma16(o, tv.z, w + 2 * TWO_E);
      sfma16(o, tv.w, w + 3 * TWO_E);
      w += 4 * TWO_E;
    }
  }
  if (valid) {
    int p0 = (wq >= 4) ? p_d : p_s;
    float4* mp = (float4*)(msgbuf + (size_t)p0 * E + (wq & 3) * 16);
    #pragma unroll
    for (int u = 0; u < 4; ++u)
      mp[u] = make_float4(o[4*u], o[4*u+1], o[4*u+2], o[4*u+3]);
  }
}

// -------- edge messages, fallback (reads h; used only if ws too small) ------
__global__ void __launch_bounds__(256) k_edge_fb(
    const int* __restrict__ rel_e, const int* __restrict__ ord0,
    const int* __restrict__ pos0, const int* __restrict__ posE1,
    const float* __restrict__ h,
    const float* __restrict__ W1, const float* __restrict__ b1,
    const float* __restrict__ W2, const float* __restrict__ b2,
    float* __restrict__ msgbuf, int me)
{
  __shared__ __align__(16) float tl[64 * 132];
  const int tid = threadIdx.x;
  const int lane = tid & 63;
  const int wq = __builtin_amdgcn_readfirstlane(tid >> 6);
  const int i = blockIdx.x * 64 + lane;
  const bool valid = (i < me);
  const int ic = valid ? i : (me - 1);
  const int e = ord0[ic];
  const int2 sd = ((const int2*)rel_e)[e];
  const int s = sd.x, d = sd.y;
  const int p_s = pos0[ic];
  const int p_d = posE1[e];
  const float4* xs4 = (const float4*)(h + (size_t)s * E);
  const float4* xd4 = (const float4*)(h + (size_t)d * E);

  float acc[32];
  {
    const float* bp = b1 + wq * 32;
    #pragma unroll
    for (int u = 0; u < 32; ++u) acc[u] = bp[u];
  }
  {
    const float* w = W1 + wq * 32;
    #pragma unroll 2
    for (int k4 = 0; k4 < 16; ++k4) {
      float4 xv = xs4[k4];
      sfma32(acc, xv.x, w);
      sfma32(acc, xv.y, w + TWO_E);
      sfma32(acc, xv.z, w + 2 * TWO_E);
      sfma32(acc, xv.w, w + 3 * TWO_E);
      w += 4 * TWO_E;
    }
    #pragma unroll 2
    for (int k4 = 0; k4 < 16; ++k4) {
      float4 xv = xd4[k4];
      sfma32(acc, xv.x, w);
      sfma32(acc, xv.y, w + TWO_E);
      sfma32(acc, xv.z, w + 2 * TWO_E);
      sfma32(acc, xv.w, w + 3 * TWO_E);
      w += 4 * TWO_E;
    }
  }
  {
    float4* trow = (float4*)&tl[lane * 132 + wq * 32];
    #pragma unroll
    for (int u = 0; u < 8; ++u)
      trow[u] = make_float4(fmaxf(acc[4*u], 0.f), fmaxf(acc[4*u+1], 0.f),
                            fmaxf(acc[4*u+2], 0.f), fmaxf(acc[4*u+3], 0.f));
  }
  __syncthreads();

  float o[32];
  {
    const float* bp = b2 + wq * 32;
    #pragma unroll
    for (int u = 0; u < 32; ++u) o[u] = bp[u];
  }
  {
    const float4* tr = (const float4*)&tl[lane * 132];
    const float* w = W2 + wq * 32;
    #pragma unroll 4
    for (int kk = 0; kk < 32; ++kk) {
      float4 tv = tr[kk];
      sfma32(o, tv.x, w);
      sfma32(o, tv.y, w + TWO_E);
      sfma32(o, tv.z, w + 2 * TWO_E);
      sfma32(o, tv.w, w + 3 * TWO_E);
      w += 4 * TWO_E;
    }
  }
  if (valid) {
    int p0 = (wq >> 1) ? p_d : p_s;
    float4* mp = (float4*)(msgbuf + (size_t)p0 * E + (wq & 1) * 32);
    #pragma unroll
    for (int u = 0; u < 8; ++u)
      mp[u] = make_float4(o[4*u], o[4*u+1], o[4*u+2], o[4*u+3]);
  }
}

// ------- gather: agg[n] += streaming sum of msgbuf[startp[n]..startp[n+1]) ----
__global__ void __launch_bounds__(256) k_gather(
    const float* __restrict__ msgbuf, const int* __restrict__ startp,
    float* __restrict__ agg, int nn)
{
  int wave = threadIdx.x >> 6;
  int j = threadIdx.x & 63;
  int n = blockIdx.x * 4 + wave;
  if (n >= nn) return;
  int s0 = startp[n], s1 = startp[n + 1];
  int cnt = s1 - s0;
  const float* p = msgbuf + (size_t)s0 * E + j;
  float v0 = 0.f, v1 = 0.f;
  int i = 0;
  for (; i + 1 < cnt; i += 2) { v0 += p[0]; v1 += p[E]; p += 2 * E; }
  if (i < cnt) v0 += p[0];
  agg[(size_t)n * E + j] += v0 + v1;
}

// ------- fused readout+proj: one block per graph (contiguous node runs) ----
__global__ void __launch_bounds__(256) k_readout_g(
    const float* __restrict__ h, const int* __restrict__ gids,
    const float* __restrict__ Wr, const float* __restrict__ br,
    float* __restrict__ g, int nn, int npg)
{
  __shared__ float ls[4][64];
  __shared__ float grow[64];
  const int j = threadIdx.x & 63;
  const int w = threadIdx.x >> 6;
  const int base = blockIdx.x * npg;
  float acc = 0.f;
  for (int i = w; i < npg; i += 4) {
    int node = base + i;
    if (node < nn) acc += h[(size_t)node * 64 + j];
  }
  ls[w][j] = acc;
  __syncthreads();
  if (w == 0) grow[j] = ls[0][j] + ls[1][j] + ls[2][j] + ls[3][j];
  __syncthreads();
  float p = 0.f;
  #pragma unroll
  for (int kk = 0; kk < 16; ++kk) {
    int k = w * 16 + kk;
    p = fmaf(grow[k], Wr[k * 64 + j], p);
  }
  ls[w][j] = p;
  __syncthreads();
  if (w == 0) {
    int gout = gids[base];
    g[gout * 64 + j] = ls[0][j] + ls[1][j] + ls[2][j] + ls[3][j] + br[j];
  }
}

// -------- node update (4-wave): wave q owns dims q*16..+16.
// h[n] += LN(MLPu([h,agg])) + LN(MLPg([h,g[gid]])). DO_NEXT: emit next
// layer's unary agg and Pab (2x32-col chunks per wave).
template <bool DO_NEXT>
__global__ void __launch_bounds__(256) k_update(
    float* __restrict__ h, float* __restrict__ agg,
    const float* __restrict__ gvec, const int* __restrict__ gids,
    const float* __restrict__ Wu1, const float* __restrict__ bu1,
    const float* __restrict__ Wu2, const float* __restrict__ bu2,
    const float* __restrict__ Wg1, const float* __restrict__ bg1,
    const float* __restrict__ Wg2, const float* __restrict__ bg2,
    const float* __restrict__ lnw, const float* __restrict__ lnb,
    const int* __restrict__ cnt_u,
    const float* __restrict__ Wmu1, const float* __restrict__ bmu1,
    const float* __restrict__ Wmu2, const float* __restrict__ bmu2,
    const float* __restrict__ W1e, const float* __restrict__ b1e,
    float* __restrict__ Pab, int do_pab, int nn)
{
  __shared__ __align__(16) float tl[64 * 68];    // 17,408 B
  __shared__ float st[64 * 9];                   // 2,304 B
  const int tid = threadIdx.x;
  const int lane = tid & 63;
  const int q = __builtin_amdgcn_readfirstlane(tid >> 6);  // 0..3, dim quarter
  const int n = blockIdx.x * 64 + lane;
  const bool valid = (n < nn);
  const int ncl = valid ? n : (nn - 1);
  const int gid = gids[ncl];
  const float4* hx = (const float4*)(h + (size_t)ncl * E);
  const float4* ax = (const float4*)(agg + (size_t)ncl * E);
  const float4* gx = (const float4*)(gvec + (size_t)gid * E);

  float res[16];

  #pragma unroll
  for (int pass = 0; pass < 2; ++pass) {
    const float* W1 = (pass == 0) ? Wu1 : Wg1;
    const float* B1 = (pass == 0) ? bu1 : bg1;
    const float* W2 = (pass == 0) ? Wu2 : Wg2;
    const float* B2 = (pass == 0) ? bu2 : bg2;
    const float4* xb = (pass == 0) ? ax : gx;

    // layer 1: hidden quarter q from 128-wide [h, xb]
    float acc[16];
    {
      const float* bp = B1 + q * 16;
      #pragma unroll
      for (int u = 0; u < 16; ++u) acc[u] = bp[u];
    }
    {
      const float* w = W1 + q * 16;        // row stride E (out dim 64)
      #pragma unroll 2
      for (int k4 = 0; k4 < 16; ++k4) {
        float4 xv = hx[k4];
        sfma16(acc, xv.x, w);
        sfma16(acc, xv.y, w + E);
        sfma16(acc, xv.z, w + 2 * E);
        sfma16(acc, xv.w, w + 3 * E);
        w += 4 * E;
      }
      #pragma unroll 2
      for (int k4 = 0; k4 < 16; ++k4) {
        float4 xv = xb[k4];
        sfma16(acc, xv.x, w);
        sfma16(acc, xv.y, w + E);
        sfma16(acc, xv.z, w + 2 * E);
        sfma16(acc, xv.w, w + 3 * E);
        w += 4 * E;
      }
    }
    {
      float4* trow = (float4*)&tl[lane * 68 + q * 16];
      #pragma unroll
      for (int u = 0; u < 4; ++u)
        trow[u] = make_float4(fmaxf(acc[4*u], 0.f), fmaxf(acc[4*u+1], 0.f),
                              fmaxf(acc[4*u+2], 0.f), fmaxf(acc[4*u+3], 0.f));
    }
    __syncthreads();

    // layer 2: output quarter q over all 64 hidden
    float o[16];
    {
      const float* bp = B2 + q * 16;
      #pragma unroll
      for (int u = 0; u < 16; ++u) o[u] = bp[u];
    }
    {
      const float4* tr = (const float4*)&tl[lane * 68];
      const float* w = W2 + q * 16;
      #pragma unroll 4
      for (int kk = 0; kk < 16; ++kk) {
        float4 tv = tr[kk];
        sfma16(o, tv.x, w);
        sfma16(o, tv.y, w + E);
        sfma16(o, tv.z, w + 2 * E);
        sfma16(o, tv.w, w + 3 * E);
        w += 4 * E;
      }
    }

    // LayerNorm across 4 waves (two-pass, matches reference form)
    float s1 = 0.f;
    #pragma unroll
    for (int u = 0; u < 16; ++u) s1 += o[u];
    st[lane * 9 + q] = s1;
    __syncthreads();
    float mu = (st[lane * 9 + 0] + st[lane * 9 + 1] +
                st[lane * 9 + 2] + st[lane * 9 + 3]) * (1.f / E);
    float s2 = 0.f;
    #pragma unroll
    for (int u = 0; u < 16; ++u) { float dm = o[u] - mu; s2 += dm * dm; }
    st[lane * 9 + 4 + q] = s2;
    __syncthreads();
    float var = (st[lane * 9 + 4] + st[lane * 9 + 5] +
                 st[lane * 9 + 6] + st[lane * 9 + 7]) * (1.f / E);
    float rs = rsqrtf(var + 1e-5f);
    {
      const float* lw = lnw + q * 16;
      const float* lb = lnb + q * 16;
      #pragma unroll
      for (int u = 0; u < 16; ++u) {
        float v = (o[u] - mu) * rs * lw[u] + lb[u];
        if (pass == 0) res[u] = v; else res[u] += v;
      }
    }
  }

  // ---- residual: h_new = h + res (quarter q) ----
  float hnew[16];
  {
    const float4* hr = (const float4*)(h + (size_t)ncl * E + q * 16);
    #pragma unroll
    for (int u = 0; u < 4; ++u) {
      float4 hv = hr[u];
      hnew[4*u+0] = hv.x + res[4*u+0];
      hnew[4*u+1] = hv.y + res[4*u+1];
      hnew[4*u+2] = hv.z + res[4*u+2];
      hnew[4*u+3] = hv.w + res[4*u+3];
    }
  }
  if (valid) {
    float4* hw = (float4*)(h + (size_t)n * E + q * 16);
    #pragma unroll
    for (int u = 0; u < 4; ++u)
      hw[u] = make_float4(hnew[4*u], hnew[4*u+1], hnew[4*u+2], hnew[4*u+3]);
  }

  if (DO_NEXT) {
    // stage h_new row in LDS (LN barriers ordered all prior tl reads)
    {
      float4* trow = (float4*)&tl[lane * 68 + q * 16];
      #pragma unroll
      for (int u = 0; u < 4; ++u)
        trow[u] = make_float4(hnew[4*u], hnew[4*u+1], hnew[4*u+2], hnew[4*u+3]);
    }
    __syncthreads();

    // unary layer 1: hidden quarter q over full 64-wide h_new
    float acc[16];
    {
      const float* bp = bmu1 + q * 16;
      #pragma unroll
      for (int u = 0; u < 16; ++u) acc[u] = bp[u];
    }
    {
      const float4* tr = (const float4*)&tl[lane * 68];
      const float* w = Wmu1 + q * 16;
      #pragma unroll 4
      for (int kk = 0; kk < 16; ++kk) {
        float4 tv = tr[kk];
        sfma16(acc, tv.x, w);
        sfma16(acc, tv.y, w + E);
        sfma16(acc, tv.z, w + 2 * E);
        sfma16(acc, tv.w, w + 3 * E);
        w += 4 * E;
      }
    }

    // PAB from h_new: wave q owns cols q*64..q*64+64, two 32-col chunks
    if (do_pab) {
      #pragma unroll 1
      for (int c = 0; c < 2; ++c) {
        const int col = q * 64 + c * 32;          // uniform
        const int rbase = (col < 128) ? 0 : 64;
        const int cw = (col < 128) ? col : (col - 128);
        float pacc[32];
        if (col < 128) {
          const float* bp = b1e + cw;
          #pragma unroll
          for (int u = 0; u < 32; ++u) pacc[u] = bp[u];
        } else {
          #pragma unroll
          for (int u = 0; u < 32; ++u) pacc[u] = 0.f;
        }
        const float4* tr = (const float4*)&tl[lane * 68];
        const float* w = W1e + rbase * TWO_E + cw;
        #pragma unroll 4
        for (int kk = 0; kk < 16; ++kk) {
          float4 tv = tr[kk];
          sfma32(pacc, tv.x, w);
          sfma32(pacc, tv.y, w + TWO_E);
          sfma32(pacc, tv.z, w + 2 * TWO_E);
          sfma32(pacc, tv.w, w + 3 * TWO_E);
          w += 4 * TWO_E;
        }
        if (valid) {
          float4* op = (float4*)(Pab + (size_t)n * 256 + col);
          #pragma unroll
          for (int u = 0; u < 8; ++u)
            op[u] = make_float4(pacc[4*u], pacc[4*u+1], pacc[4*u+2], pacc[4*u+3]);
        }
      }
    }
    __syncthreads();        // all reads of h_new done before overwrite
    {
      float4* trow = (float4*)&tl[lane * 68 + q * 16];
      #pragma unroll
      for (int u = 0; u < 4; ++u)
        trow[u] = make_float4(fmaxf(acc[4*u], 0.f), fmaxf(acc[4*u+1], 0.f),
                              fmaxf(acc[4*u+2], 0.f), fmaxf(acc[4*u+3], 0.f));
    }
    __syncthreads();

    // unary layer 2: output quarter q over all 64 hidden; agg = cf * msg
    float o[16];
    {
      const float* bp = bmu2 + q * 16;
      #pragma unroll
      for (int u = 0; u < 16; ++u) o[u] = bp[u];
    }
    {
      const float4* tr = (const float4*)&tl[lane * 68];
      const float* w = Wmu2 + q * 16;
      #pragma unroll 4
      for (int kk = 0; kk < 16; ++kk) {
        float4 tv = tr[kk];
        sfma16(o, tv.x, w);
        sfma16(o, tv.y, w + E);
        sfma16(o, tv.z, w + 2 * E);
        sfma16(o, tv.w, w + 3 * E);
        w += 4 * E;
      }
    }
    if (valid) {
      float cf = (float)cnt_u[n];
      float4* ap = (float4*)(agg + (size_t)n * E + q * 16);
      #pragma unroll
      for (int u = 0; u < 4; ++u)
        ap[u] = make_float4(o[4*u] * cf, o[4*u+1] * cf, o[4*u+2] * cf, o[4*u+3] * cf);
    }
  }
}

extern "C" void kernel_launch(void* const* d_in, const int* in_sizes, int n_in,
                              void* d_out, int out_size, void* d_ws, size_t ws_size,
                              hipStream_t stream) {
  (void)n_in; (void)out_size;
  const int*   rel_u = (const int*)d_in[0];
  const int*   rel_e = (const int*)d_in[1];
  const int*   gids  = (const int*)d_in[2];
  const float* Wm1_u = (const float*)d_in[4];
  const float* bm1_u = (const float*)d_in[5];
  const float* Wm2_u = (const float*)d_in[6];
  const float* bm2_u = (const float*)d_in[7];
  const float* Wm1_e = (const float*)d_in[8];
  const float* bm1_e = (const float*)d_in[9];
  const float* Wm2_e = (const float*)d_in[10];
  const float* bm2_e = (const float*)d_in[11];
  const float* Wu1   = (const float*)d_in[12];
  const float* bu1   = (const float*)d_in[13];
  const float* Wu2   = (const float*)d_in[14];
  const float* bu2   = (const float*)d_in[15];
  const float* lnw   = (const float*)d_in[16];
  const float* lnb   = (const float*)d_in[17];
  const float* Wr    = (const float*)d_in[18];
  const float* br    = (const float*)d_in[19];
  const float* Wg1   = (const float*)d_in[20];
  const float* bg1   = (const float*)d_in[21];
  const float* Wg2   = (const float*)d_in[22];
  const float* bg2   = (const float*)d_in[23];

  const int MU_ = in_sizes[0];          // 100000
  const int ME_ = in_sizes[1] / 2;      // 200000
  const int NN  = in_sizes[2];          // 50000
  const int GN  = 100;
  const int NPG = NN / GN;              // 500 nodes per graph (contiguous)
  const int M2  = 2 * ME_;              // 400000 edge message slots
  const int NB  = (NN + 255) / 256;     // scan blocks (196 <= 256)
  const int NBW = (NN + 256) / 256;     // k_wstart covers i = 0..NN
  const int NBU = (NN + 63) / 64;       // k_update blocks (782)

  // ---- workspace layout ----
  float* h       = (float*)d_out;
  float* agg     = (float*)d_ws;                           // [N*64]
  float* g       = agg + (size_t)NN * E;                   // [G*64]
  float* mu0     = g + (size_t)GN * E;                     // [64]
  float* me0     = mu0 + 64;                               // [128]
  float* msgbuf  = me0 + TWO_E;                            // [M2*64]
  int*   cpos0   = (int*)(msgbuf + (size_t)M2 * E);        // [N]
  int*   cpos1   = cpos0 + NN;                             // [N]
  int*   cnt_u   = cpos1 + NN;                             // [N]
  int*   startp  = cnt_u + NN;                             // [N+1]
  int*   startp0 = startp + NN + 1;                        // [N+1]
  int*   startp1 = startp0 + NN + 1;                       // [N+1]
  int*   cur0    = startp1 + NN + 1;                       // [N+1]
  int*   cur1    = cur0 + NN + 1;                          // [N+1]
  int*   ord0    = cur1 + NN + 1;                          // [ME]
  int*   pos0    = ord0 + ME_;                             // [ME]
  int*   posE1   = pos0 + ME_;                             // [ME]
  int*   bsum    = posE1 + ME_;                            // [2*NB]
  int*   boff    = bsum + 2 * NB;                          // [2*NB]
  size_t int_end = (size_t)(boff + 2 * NB - (int*)d_ws);
  size_t pab_off = (int_end + 3) & ~(size_t)3;
  float* Pab     = (float*)d_ws + pab_off;                 // [N*256]
  size_t need_pab = (pab_off + (size_t)NN * 256) * 4;
  const bool pab_mode = (ws_size >= need_pab);

  { // h = 0
    int n4 = NN * E / 4;
    k_zero<<<(n4 + 255) / 256, 256, 0, stream>>>((float4*)h, n4);
  }
  { // zero [cpos0, cpos1, cnt_u] (3N ints; small spill into startp is ok)
    int n4 = (3 * NN + 4) / 4;
    k_zero<<<(n4 + 255) / 256, 256, 0, stream>>>((float4*)cpos0, n4);
  }
  // ---- CSR + counts + constant messages (once; graph static) ----
  k_count_e<<<(ME_ + 255) / 256, 256, 0, stream>>>(rel_e, cpos0, cpos1, ME_);
  k_count_u<<<(MU_ + 255) / 256, 256, 0, stream>>>(rel_u, cnt_u, MU_);
  k_bsum<<<NB, 256, 0, stream>>>(cpos0, cpos1, bsum, NN, NB);
  k_scanblk<<<1, 256, 0, stream>>>(bsum, boff, NB);
  k_wstart<<<NBW, 256, 0, stream>>>(cpos0, cpos1, boff, startp, startp0, startp1,
                                    cur0, cur1, NN, NB, ME_);
  k_fill_e<<<(ME_ + 255) / 256, 256, 0, stream>>>(
      rel_e, startp, startp0, startp1, cpos0, cur0, cur1, ord0, pos0, posE1, ME_);
  k_mlp0<<<1, 128, 0, stream>>>(bm1_u, Wm2_u, bm2_u, bm1_e, Wm2_e, bm2_e,
                                br, mu0, me0, g, GN);

  // ---- layer 0: messages constant; g = br; update emits unary agg + Pab ----
  k_agg0<<<(NN * 16 + 255) / 256, 256, 0, stream>>>(cnt_u, cpos0, cpos1, mu0, me0, agg, NN);
  k_update<true><<<NBU, 256, 0, stream>>>(
      h, agg, g, gids, Wu1, bu1, Wu2, bu2, Wg1, bg1, Wg2, bg2, lnw, lnb,
      cnt_u, Wm1_u, bm1_u, Wm2_u, bm2_u, Wm1_e, bm1_e, Pab, pab_mode ? 1 : 0, NN);

  // ---- layers 1..3 ----
  for (int l = 1; l < 4; ++l) {
    if (pab_mode)
      k_edge_pab<<<(ME_ + 63) / 64, 512, 0, stream>>>(
          rel_e, ord0, pos0, posE1, Pab, Wm2_e, bm2_e, msgbuf, ME_);
    else
      k_edge_fb<<<(ME_ + 63) / 64, 256, 0, stream>>>(
          rel_e, ord0, pos0, posE1, h, Wm1_e, bm1_e, Wm2_e, bm2_e, msgbuf, ME_);
    k_gather<<<(NN + 3) / 4, 256, 0, stream>>>(msgbuf, startp, agg, NN);
    k_readout_g<<<GN, 256, 0, stream>>>(h, gids, Wr, br, g, NN, NPG);
    if (l < 3)
      k_update<true><<<NBU, 256, 0, stream>>>(
          h, agg, g, gids, Wu1, bu1, Wu2, bu2, Wg1, bg1, Wg2, bg2, lnw, lnb,
          cnt_u, Wm1_u, bm1_u, Wm2_u, bm2_u, Wm1_e, bm1_e, Pab, pab_mode ? 1 : 0, NN);
    else
      k_update<false><<<NBU, 256, 0, stream>>>(
          h, agg, g, gids, Wu1, bu1, Wu2, bu2, Wg1, bg1, Wg2, bg2, lnw, lnb,
          cnt_u, Wm1_u, bm1_u, Wm2_u, bm2_u, Wm1_e, bm1_e, Pab, 0, NN);
  }
}

// Round 17
// 815.743 us; speedup vs baseline: 1.8408x; 1.0261x over previous
//
#include <hip/hip_runtime.h>

// Round 17: parallel-pass k_update. MLPu (waves 0-1) and MLPg (waves 2-3) run
// CONCURRENTLY (they're independent until the residual sum); the serial
// {layer1, barrier, layer2, 2xLN-barrier} chain executes once instead of
// twice. LN combines within wave pairs; gm merged into residual via one LDS
// exchange. Epilogue (fused unary msg + Pab) unchanged. Everything else = R16.

#define E 64
#define TWO_E 128

__device__ __forceinline__ void sfma32(float (&acc)[32], float xu, const float* w) {
  #pragma unroll
  for (int i = 0; i < 32; ++i) acc[i] = fmaf(xu, w[i], acc[i]);
}
__device__ __forceinline__ void sfma16(float (&acc)[16], float xu, const float* w) {
  #pragma unroll
  for (int i = 0; i < 16; ++i) acc[i] = fmaf(xu, w[i], acc[i]);
}

// ---------------- zero ----------------
__global__ void k_zero(float4* __restrict__ p, int n4) {
  int i = blockIdx.x * blockDim.x + threadIdx.x;
  if (i < n4) p[i] = make_float4(0.f, 0.f, 0.f, 0.f);
}

// ---------------- counts (per edge / per atom) ----------------
__global__ void k_count_e(const int* __restrict__ rel_e, int* __restrict__ cpos0,
                          int* __restrict__ cpos1, int me) {
  int e = blockIdx.x * blockDim.x + threadIdx.x;
  if (e >= me) return;
  int2 sd = ((const int2*)rel_e)[e];
  atomicAdd(&cpos0[sd.x], 1);
  atomicAdd(&cpos1[sd.y], 1);
}
__global__ void k_count_u(const int* __restrict__ rel_u, int* __restrict__ cnt_u, int mu) {
  int m = blockIdx.x * blockDim.x + threadIdx.x;
  if (m >= mu) return;
  atomicAdd(&cnt_u[rel_u[m]], 1);
}

// ------- multi-block scan, phase 1: per-block sums of cpos0/cpos1 -------
__global__ void __launch_bounds__(256) k_bsum(
    const int* __restrict__ cpos0, const int* __restrict__ cpos1,
    int* __restrict__ bsum, int nn, int nb) {
  __shared__ int l0[256], l1[256];
  int t = threadIdx.x, b = blockIdx.x;
  int i = b * 256 + t;
  l0[t] = (i < nn) ? cpos0[i] : 0;
  l1[t] = (i < nn) ? cpos1[i] : 0;
  __syncthreads();
  for (int off = 128; off > 0; off >>= 1) {
    if (t < off) { l0[t] += l0[t + off]; l1[t] += l1[t + off]; }
    __syncthreads();
  }
  if (t == 0) { bsum[b] = l0[0]; bsum[nb + b] = l1[0]; }
}

// ------- phase 2: exclusive scan of the (<=256) block sums -------
__global__ void __launch_bounds__(256) k_scanblk(
    const int* __restrict__ bsum, int* __restrict__ boff, int nb) {
  __shared__ int l0[256], l1[256];
  int t = threadIdx.x;
  int o0 = (t < nb) ? bsum[t] : 0;
  int o1 = (t < nb) ? bsum[nb + t] : 0;
  l0[t] = o0; l1[t] = o1;
  __syncthreads();
  for (int off = 1; off < 256; off <<= 1) {
    int v0 = (t >= off) ? l0[t - off] : 0;
    int v1 = (t >= off) ? l1[t - off] : 0;
    __syncthreads();
    l0[t] += v0; l1[t] += v1;
    __syncthreads();
  }
  if (t < nb) { boff[t] = l0[t] - o0; boff[nb + t] = l1[t] - o1; }
}

// ------- phase 3: per-block exclusive scan + offsets; writes startp*/cur* ----
__global__ void __launch_bounds__(256) k_wstart(
    const int* __restrict__ cpos0, const int* __restrict__ cpos1,
    const int* __restrict__ boff,
    int* __restrict__ startp, int* __restrict__ startp0, int* __restrict__ startp1,
    int* __restrict__ cur0, int* __restrict__ cur1, int nn, int nb, int me) {
  __shared__ int l0[256], l1[256];
  int t = threadIdx.x, b = blockIdx.x;
  int i = b * 256 + t;
  int c0 = (i < nn) ? cpos0[i] : 0;
  int c1 = (i < nn) ? cpos1[i] : 0;
  l0[t] = c0; l1[t] = c1;
  __syncthreads();
  for (int off = 1; off < 256; off <<= 1) {
    int v0 = (t >= off) ? l0[t - off] : 0;
    int v1 = (t >= off) ? l1[t - off] : 0;
    __syncthreads();
    l0[t] += v0; l1[t] += v1;
    __syncthreads();
  }
  if (i < nn) {
    int s0 = boff[b] + l0[t] - c0;          // exclusive prefix
    int s1 = boff[nb + b] + l1[t] - c1;
    startp0[i] = s0; startp1[i] = s1; startp[i] = s0 + s1;
    cur0[i] = s0; cur1[i] = s1;
  }
  if (i == nn) { startp0[nn] = me; startp1[nn] = me; startp[nn] = 2 * me; }
}

// fill: ord0 (edges sorted by s), pos0 (msgbuf pos of ->s msg), posE1[e] (->d msg)
__global__ void k_fill_e(const int* __restrict__ rel_e,
                         const int* __restrict__ startp, const int* __restrict__ startp0,
                         const int* __restrict__ startp1, const int* __restrict__ cpos0,
                         int* __restrict__ cur0, int* __restrict__ cur1,
                         int* __restrict__ ord0, int* __restrict__ pos0,
                         int* __restrict__ posE1, int me) {
  int e = blockIdx.x * blockDim.x + threadIdx.x;
  if (e >= me) return;
  int2 sd = ((const int2*)rel_e)[e];
  int s = sd.x, d = sd.y;
  int i0 = atomicAdd(&cur0[s], 1);
  ord0[i0] = e;
  pos0[i0] = startp[s] + (i0 - startp0[s]);
  int i1 = atomicAdd(&cur1[d], 1);
  posE1[e] = startp[d] + cpos0[d] + (i1 - startp1[d]);
}

// ------- mu0 = MLP_u(0), me0 = MLP_e(0); also g(layer0) = br for all graphs ----
__global__ void k_mlp0(const float* __restrict__ b1u, const float* __restrict__ W2u,
                       const float* __restrict__ b2u,
                       const float* __restrict__ b1e, const float* __restrict__ W2e,
                       const float* __restrict__ b2e,
                       const float* __restrict__ br,
                       float* __restrict__ mu0, float* __restrict__ me0,
                       float* __restrict__ g, int gn) {
  __shared__ float hu[64], he[128];
  int t = threadIdx.x;                     // 128 threads
  if (t < 64) hu[t] = fmaxf(b1u[t], 0.f);
  he[t] = fmaxf(b1e[t], 0.f);
  __syncthreads();
  if (t < 64) {
    float a = b2u[t];
    for (int k = 0; k < 64; ++k) a = fmaf(hu[k], W2u[k * 64 + t], a);
    mu0[t] = a;
  }
  float a = b2e[t];
  for (int k = 0; k < 128; ++k) a = fmaf(he[k], W2e[k * TWO_E + t], a);
  me0[t] = a;
  if (t < 64) {
    float b = br[t];
    for (int gi = 0; gi < gn; ++gi) g[gi * 64 + t] = b;
  }
}

// ------- layer-0 agg from counts ----------
__global__ void k_agg0(const int* __restrict__ cnt_u, const int* __restrict__ cpos0,
                       const int* __restrict__ cpos1, const float* __restrict__ mu0,
                       const float* __restrict__ me0, float* __restrict__ agg, int nn) {
  int i = blockIdx.x * blockDim.x + threadIdx.x;   // (n, j4)
  int n = i >> 4, j4 = i & 15;
  if (n >= nn) return;
  float cu = (float)cnt_u[n], c0 = (float)cpos0[n], c1 = (float)cpos1[n];
  float4 m = ((const float4*)mu0)[j4];
  float4 a = ((const float4*)me0)[j4];
  float4 b = ((const float4*)(me0 + 64))[j4];
  ((float4*)agg)[i] = make_float4(cu * m.x + c0 * a.x + c1 * b.x,
                                  cu * m.y + c0 * a.y + c1 * b.y,
                                  cu * m.z + c0 * a.z + c1 * b.z,
                                  cu * m.w + c0 * a.w + c1 * b.w);
}

// -------- edge messages, PAB mode, 8 waves / 64 edges (unchanged R16) -------
__global__ void __launch_bounds__(512) k_edge_pab(
    const int* __restrict__ rel_e, const int* __restrict__ ord0,
    const int* __restrict__ pos0, const int* __restrict__ posE1,
    const float* __restrict__ Pab,
    const float* __restrict__ W2, const float* __restrict__ b2,
    float* __restrict__ msgbuf, int me)
{
  __shared__ __align__(16) float tl[64 * 132];
  const int tid = threadIdx.x;
  const int lane = tid & 63;
  const int wq = __builtin_amdgcn_readfirstlane(tid >> 6);   // 0..7
  const int i = blockIdx.x * 64 + lane;
  const bool valid = (i < me);
  const int ic = valid ? i : (me - 1);
  const int e = ord0[ic];
  const int2 sd = ((const int2*)rel_e)[e];
  const int s = sd.x, d = sd.y;
  const int p_s = pos0[ic];
  const int p_d = posE1[e];

  {
    const float4* pa = (const float4*)(Pab + (size_t)s * 256 + wq * 16);
    const float4* pb = (const float4*)(Pab + (size_t)d * 256 + 128 + wq * 16);
    float4* trow = (float4*)&tl[lane * 132 + wq * 16];
    #pragma unroll
    for (int u = 0; u < 4; ++u) {
      float4 va = pa[u], vb = pb[u];
      trow[u] = make_float4(fmaxf(va.x + vb.x, 0.f), fmaxf(va.y + vb.y, 0.f),
                            fmaxf(va.z + vb.z, 0.f), fmaxf(va.w + vb.w, 0.f));
    }
  }
  __syncthreads();

  float o[16];
  {
    const float* bp = b2 + wq * 16;
    #pragma unroll
    for (int u = 0; u < 16; ++u) o[u] = bp[u];
  }
  {
    const float4* tr = (const float4*)&tl[lane * 132];
    const float* w = W2 + wq * 16;          // row stride TWO_E, 128 rows
    #pragma unroll 4
    for (int kk = 0; kk < 32; ++kk) {
      float4 tv = tr[kk];
      sfma16(o, tv.x, w);
      sfma16(o, tv.y, w + TWO_E);
      sfma16(o, tv.z, w + 2 * TWO_E);
      sfma16(o, tv.w, w + 3 * TWO_E);
      w += 4 * TWO_E;
    }
  }
  if (valid) {
    int p0 = (wq >= 4) ? p_d : p_s;
    float4* mp = (float4*)(msgbuf + (size_t)p0 * E + (wq & 3) * 16);
    #pragma unroll
    for (int u = 0; u < 4; ++u)
      mp[u] = make_float4(o[4*u], o[4*u+1], o[4*u+2], o[4*u+3]);
  }
}

// -------- edge messages, fallback (reads h; used only if ws too small) ------
__global__ void __launch_bounds__(256) k_edge_fb(
    const int* __restrict__ rel_e, const int* __restrict__ ord0,
    const int* __restrict__ pos0, const int* __restrict__ posE1,
    const float* __restrict__ h,
    const float* __restrict__ W1, const float* __restrict__ b1,
    const float* __restrict__ W2, const float* __restrict__ b2,
    float* __restrict__ msgbuf, int me)
{
  __shared__ __align__(16) float tl[64 * 132];
  const int tid = threadIdx.x;
  const int lane = tid & 63;
  const int wq = __builtin_amdgcn_readfirstlane(tid >> 6);
  const int i = blockIdx.x * 64 + lane;
  const bool valid = (i < me);
  const int ic = valid ? i : (me - 1);
  const int e = ord0[ic];
  const int2 sd = ((const int2*)rel_e)[e];
  const int s = sd.x, d = sd.y;
  const int p_s = pos0[ic];
  const int p_d = posE1[e];
  const float4* xs4 = (const float4*)(h + (size_t)s * E);
  const float4* xd4 = (const float4*)(h + (size_t)d * E);

  float acc[32];
  {
    const float* bp = b1 + wq * 32;
    #pragma unroll
    for (int u = 0; u < 32; ++u) acc[u] = bp[u];
  }
  {
    const float* w = W1 + wq * 32;
    #pragma unroll 2
    for (int k4 = 0; k4 < 16; ++k4) {
      float4 xv = xs4[k4];
      sfma32(acc, xv.x, w);
      sfma32(acc, xv.y, w + TWO_E);
      sfma32(acc, xv.z, w + 2 * TWO_E);
      sfma32(acc, xv.w, w + 3 * TWO_E);
      w += 4 * TWO_E;
    }
    #pragma unroll 2
    for (int k4 = 0; k4 < 16; ++k4) {
      float4 xv = xd4[k4];
      sfma32(acc, xv.x, w);
      sfma32(acc, xv.y, w + TWO_E);
      sfma32(acc, xv.z, w + 2 * TWO_E);
      sfma32(acc, xv.w, w + 3 * TWO_E);
      w += 4 * TWO_E;
    }
  }
  {
    float4* trow = (float4*)&tl[lane * 132 + wq * 32];
    #pragma unroll
    for (int u = 0; u < 8; ++u)
      trow[u] = make_float4(fmaxf(acc[4*u], 0.f), fmaxf(acc[4*u+1], 0.f),
                            fmaxf(acc[4*u+2], 0.f), fmaxf(acc[4*u+3], 0.f));
  }
  __syncthreads();

  float o[32];
  {
    const float* bp = b2 + wq * 32;
    #pragma unroll
    for (int u = 0; u < 32; ++u) o[u] = bp[u];
  }
  {
    const float4* tr = (const float4*)&tl[lane * 132];
    const float* w = W2 + wq * 32;
    #pragma unroll 4
    for (int kk = 0; kk < 32; ++kk) {
      float4 tv = tr[kk];
      sfma32(o, tv.x, w);
      sfma32(o, tv.y, w + TWO_E);
      sfma32(o, tv.z, w + 2 * TWO_E);
      sfma32(o, tv.w, w + 3 * TWO_E);
      w += 4 * TWO_E;
    }
  }
  if (valid) {
    int p0 = (wq >> 1) ? p_d : p_s;
    float4* mp = (float4*)(msgbuf + (size_t)p0 * E + (wq & 1) * 32);
    #pragma unroll
    for (int u = 0; u < 8; ++u)
      mp[u] = make_float4(o[4*u], o[4*u+1], o[4*u+2], o[4*u+3]);
  }
}

// ------- gather: agg[n] += streaming sum of msgbuf[startp[n]..startp[n+1]) ----
__global__ void __launch_bounds__(256) k_gather(
    const float* __restrict__ msgbuf, const int* __restrict__ startp,
    float* __restrict__ agg, int nn)
{
  int wave = threadIdx.x >> 6;
  int j = threadIdx.x & 63;
  int n = blockIdx.x * 4 + wave;
  if (n >= nn) return;
  int s0 = startp[n], s1 = startp[n + 1];
  int cnt = s1 - s0;
  const float* p = msgbuf + (size_t)s0 * E + j;
  float v0 = 0.f, v1 = 0.f;
  int i = 0;
  for (; i + 1 < cnt; i += 2) { v0 += p[0]; v1 += p[E]; p += 2 * E; }
  if (i < cnt) v0 += p[0];
  agg[(size_t)n * E + j] += v0 + v1;
}

// ------- fused readout+proj: one block per graph (contiguous node runs) ----
__global__ void __launch_bounds__(256) k_readout_g(
    const float* __restrict__ h, const int* __restrict__ gids,
    const float* __restrict__ Wr, const float* __restrict__ br,
    float* __restrict__ g, int nn, int npg)
{
  __shared__ float ls[4][64];
  __shared__ float grow[64];
  const int j = threadIdx.x & 63;
  const int w = threadIdx.x >> 6;
  const int base = blockIdx.x * npg;
  float acc = 0.f;
  for (int i = w; i < npg; i += 4) {
    int node = base + i;
    if (node < nn) acc += h[(size_t)node * 64 + j];
  }
  ls[w][j] = acc;
  __syncthreads();
  if (w == 0) grow[j] = ls[0][j] + ls[1][j] + ls[2][j] + ls[3][j];
  __syncthreads();
  float p = 0.f;
  #pragma unroll
  for (int kk = 0; kk < 16; ++kk) {
    int k = w * 16 + kk;
    p = fmaf(grow[k], Wr[k * 64 + j], p);
  }
  ls[w][j] = p;
  __syncthreads();
  if (w == 0) {
    int gout = gids[base];
    g[gout * 64 + j] = ls[0][j] + ls[1][j] + ls[2][j] + ls[3][j] + br[j];
  }
}

// -------- node update, PARALLEL passes: waves 0-1 = MLPu (32-dim halves),
// waves 2-3 = MLPg. LN within wave pairs; gm merged via LDS exchange.
// DO_NEXT: emit next layer's unary agg (16-dim quarters) and Pab (64 cols/wave).
template <bool DO_NEXT>
__global__ void __launch_bounds__(256) k_update(
    float* __restrict__ h, float* __restrict__ agg,
    const float* __restrict__ gvec, const int* __restrict__ gids,
    const float* __restrict__ Wu1, const float* __restrict__ bu1,
    const float* __restrict__ Wu2, const float* __restrict__ bu2,
    const float* __restrict__ Wg1, const float* __restrict__ bg1,
    const float* __restrict__ Wg2, const float* __restrict__ bg2,
    const float* __restrict__ lnw, const float* __restrict__ lnb,
    const int* __restrict__ cnt_u,
    const float* __restrict__ Wmu1, const float* __restrict__ bmu1,
    const float* __restrict__ Wmu2, const float* __restrict__ bmu2,
    const float* __restrict__ W1e, const float* __restrict__ b1e,
    float* __restrict__ Pab, int do_pab, int nn)
{
  __shared__ __align__(16) float tlu[64 * 68];   // MLPu hidden; later h_new
  __shared__ __align__(16) float tlg[64 * 68];   // MLPg hidden; later gm / umsg hidden
  __shared__ float st[64 * 9];
  const int tid = threadIdx.x;
  const int lane = tid & 63;
  const int w = __builtin_amdgcn_readfirstlane(tid >> 6);  // 0..3, uniform
  const int hf = w & 1;                 // 32-dim half within own MLP
  const int pbase = w & 2;              // LN pair base (0 or 2)
  const bool isU = (w < 2);
  const int n = blockIdx.x * 64 + lane;
  const bool valid = (n < nn);
  const int ncl = valid ? n : (nn - 1);
  const int gid = gids[ncl];
  const float4* hx = (const float4*)(h + (size_t)ncl * E);
  const float4* xb = isU ? (const float4*)(agg + (size_t)ncl * E)
                         : (const float4*)(gvec + (size_t)gid * E);
  const float* W1 = isU ? Wu1 : Wg1;
  const float* B1 = isU ? bu1 : bg1;
  const float* W2 = isU ? Wu2 : Wg2;
  const float* B2 = isU ? bu2 : bg2;
  float* tlmine = isU ? tlu : tlg;

  // ---- layer 1: own MLP, hidden half hf, from 128-wide [h, xb] ----
  float acc[32];
  {
    const float* bp = B1 + hf * 32;
    #pragma unroll
    for (int u = 0; u < 32; ++u) acc[u] = bp[u];
  }
  {
    const float* wp = W1 + hf * 32;      // row stride E (out dim 64)
    #pragma unroll 2
    for (int k4 = 0; k4 < 16; ++k4) {
      float4 xv = hx[k4];
      sfma32(acc, xv.x, wp);
      sfma32(acc, xv.y, wp + E);
      sfma32(acc, xv.z, wp + 2 * E);
      sfma32(acc, xv.w, wp + 3 * E);
      wp += 4 * E;
    }
    #pragma unroll 2
    for (int k4 = 0; k4 < 16; ++k4) {
      float4 xv = xb[k4];
      sfma32(acc, xv.x, wp);
      sfma32(acc, xv.y, wp + E);
      sfma32(acc, xv.z, wp + 2 * E);
      sfma32(acc, xv.w, wp + 3 * E);
      wp += 4 * E;
    }
  }
  {
    float4* trow = (float4*)&tlmine[lane * 68 + hf * 32];
    #pragma unroll
    for (int u = 0; u < 8; ++u)
      trow[u] = make_float4(fmaxf(acc[4*u], 0.f), fmaxf(acc[4*u+1], 0.f),
                            fmaxf(acc[4*u+2], 0.f), fmaxf(acc[4*u+3], 0.f));
  }
  __syncthreads();

  // ---- layer 2: own MLP, output half hf, over own MLP's 64 hidden ----
  float o[32];
  {
    const float* bp = B2 + hf * 32;
    #pragma unroll
    for (int u = 0; u < 32; ++u) o[u] = bp[u];
  }
  {
    const float4* tr = (const float4*)&tlmine[lane * 68];
    const float* wp = W2 + hf * 32;
    #pragma unroll 4
    for (int kk = 0; kk < 16; ++kk) {
      float4 tv = tr[kk];
      sfma32(o, tv.x, wp);
      sfma32(o, tv.y, wp + E);
      sfma32(o, tv.z, wp + 2 * E);
      sfma32(o, tv.w, wp + 3 * E);
      wp += 4 * E;
    }
  }

  // ---- LayerNorm within wave pair (two-pass, matches reference form) ----
  {
    float s1 = 0.f;
    #pragma unroll
    for (int u = 0; u < 32; ++u) s1 += o[u];
    st[lane * 9 + w] = s1;
    __syncthreads();
    float mu = (st[lane * 9 + pbase] + st[lane * 9 + pbase + 1]) * (1.f / E);
    float s2 = 0.f;
    #pragma unroll
    for (int u = 0; u < 32; ++u) { float dm = o[u] - mu; s2 += dm * dm; }
    st[lane * 9 + 4 + w] = s2;
    __syncthreads();
    float var = (st[lane * 9 + 4 + pbase] + st[lane * 9 + 5 + pbase]) * (1.f / E);
    float rs = rsqrtf(var + 1e-5f);
    const float* lw = lnw + hf * 32;
    const float* lb = lnb + hf * 32;
    #pragma unroll
    for (int u = 0; u < 32; ++u)
      o[u] = (o[u] - mu) * rs * lw[u] + lb[u];
  }

  // ---- exchange: waves 2-3 publish gm halves (tlg hidden fully consumed) ----
  if (!isU) {
    float4* gp = (float4*)&tlg[lane * 68 + hf * 32];
    #pragma unroll
    for (int u = 0; u < 8; ++u)
      gp[u] = make_float4(o[4*u], o[4*u+1], o[4*u+2], o[4*u+3]);
  }
  __syncthreads();

  // ---- residual (waves 0-1): h_new = h + nxt + gm; write h ----
  float hnew[32];
  if (isU) {
    const float4* gp = (const float4*)&tlg[lane * 68 + hf * 32];
    const float4* hr = (const float4*)(h + (size_t)ncl * E + hf * 32);
    #pragma unroll
    for (int u = 0; u < 8; ++u) {
      float4 hv = hr[u], gv = gp[u];
      hnew[4*u+0] = hv.x + o[4*u+0] + gv.x;
      hnew[4*u+1] = hv.y + o[4*u+1] + gv.y;
      hnew[4*u+2] = hv.z + o[4*u+2] + gv.z;
      hnew[4*u+3] = hv.w + o[4*u+3] + gv.w;
    }
    if (valid) {
      float4* hw = (float4*)(h + (size_t)n * E + hf * 32);
      #pragma unroll
      for (int u = 0; u < 8; ++u)
        hw[u] = make_float4(hnew[4*u], hnew[4*u+1], hnew[4*u+2], hnew[4*u+3]);
    }
  }

  if (DO_NEXT) {
    // stage h_new in tlu (its hidden fully consumed pre-LN-barriers)
    if (isU) {
      float4* trow = (float4*)&tlu[lane * 68 + hf * 32];
      #pragma unroll
      for (int u = 0; u < 8; ++u)
        trow[u] = make_float4(hnew[4*u], hnew[4*u+1], hnew[4*u+2], hnew[4*u+3]);
    }
    __syncthreads();

    // unary layer 1: hidden quarter w over full 64-wide h_new (tlu)
    float uacc[16];
    {
      const float* bp = bmu1 + w * 16;
      #pragma unroll
      for (int u = 0; u < 16; ++u) uacc[u] = bp[u];
    }
    {
      const float4* tr = (const float4*)&tlu[lane * 68];
      const float* wp = Wmu1 + w * 16;
      #pragma unroll 4
      for (int kk = 0; kk < 16; ++kk) {
        float4 tv = tr[kk];
        sfma16(uacc, tv.x, wp);
        sfma16(uacc, tv.y, wp + E);
        sfma16(uacc, tv.z, wp + 2 * E);
        sfma16(uacc, tv.w, wp + 3 * E);
        wp += 4 * E;
      }
    }

    // PAB from h_new (tlu): wave w owns cols w*64..+64, two 32-col chunks
    if (do_pab) {
      #pragma unroll 1
      for (int c = 0; c < 2; ++c) {
        const int col = w * 64 + c * 32;          // uniform
        const int rbase = (col < 128) ? 0 : 64;
        const int cw = (col < 128) ? col : (col - 128);
        float pacc[32];
        if (col < 128) {
          const float* bp = b1e + cw;
          #pragma unroll
          for (int u = 0; u < 32; ++u) pacc[u] = bp[u];
        } else {
          #pragma unroll
          for (int u = 0; u < 32; ++u) pacc[u] = 0.f;
        }
        const float4* tr = (const float4*)&tlu[lane * 68];
        const float* wp = W1e + rbase * TWO_E + cw;
        #pragma unroll 4
        for (int kk = 0; kk < 16; ++kk) {
          float4 tv = tr[kk];
          sfma32(pacc, tv.x, wp);
          sfma32(pacc, tv.y, wp + TWO_E);
          sfma32(pacc, tv.z, wp + 2 * TWO_E);
          sfma32(pacc, tv.w, wp + 3 * TWO_E);
          wp += 4 * TWO_E;
        }
        if (valid) {
          float4* op = (float4*)(Pab + (size_t)n * 256 + col);
          #pragma unroll
          for (int u = 0; u < 8; ++u)
            op[u] = make_float4(pacc[4*u], pacc[4*u+1], pacc[4*u+2], pacc[4*u+3]);
        }
      }
    }
    __syncthreads();      // all tlg reads (residual) + tlu reads done

    // stage relu(unary hidden) into tlg (free now)
    {
      float4* trow = (float4*)&tlg[lane * 68 + w * 16];
      #pragma unroll
      for (int u = 0; u < 4; ++u)
        trow[u] = make_float4(fmaxf(uacc[4*u], 0.f), fmaxf(uacc[4*u+1], 0.f),
                              fmaxf(uacc[4*u+2], 0.f), fmaxf(uacc[4*u+3], 0.f));
    }
    __syncthreads();

    // unary layer 2: output quarter w over 64 hidden (tlg); agg = cf * msg
    float uo[16];
    {
      const float* bp = bmu2 + w * 16;
      #pragma unroll
      for (int u = 0; u < 16; ++u) uo[u] = bp[u];
    }
    {
      const float4* tr = (const float4*)&tlg[lane * 68];
      const float* wp = Wmu2 + w * 16;
      #pragma unroll 4
      for (int kk = 0; kk < 16; ++kk) {
        float4 tv = tr[kk];
        sfma16(uo, tv.x, wp);
        sfma16(uo, tv.y, wp + E);
        sfma16(uo, tv.z, wp + 2 * E);
        sfma16(uo, tv.w, wp + 3 * E);
        wp += 4 * E;
      }
    }
    if (valid) {
      float cf = (float)cnt_u[n];
      float4* ap = (float4*)(agg + (size_t)n * E + w * 16);
      #pragma unroll
      for (int u = 0; u < 4; ++u)
        ap[u] = make_float4(uo[4*u] * cf, uo[4*u+1] * cf, uo[4*u+2] * cf, uo[4*u+3] * cf);
    }
  }
}

extern "C" void kernel_launch(void* const* d_in, const int* in_sizes, int n_in,
                              void* d_out, int out_size, void* d_ws, size_t ws_size,
                              hipStream_t stream) {
  (void)n_in; (void)out_size;
  const int*   rel_u = (const int*)d_in[0];
  const int*   rel_e = (const int*)d_in[1];
  const int*   gids  = (const int*)d_in[2];
  const float* Wm1_u = (const float*)d_in[4];
  const float* bm1_u = (const float*)d_in[5];
  const float* Wm2_u = (const float*)d_in[6];
  const float* bm2_u = (const float*)d_in[7];
  const float* Wm1_e = (const float*)d_in[8];
  const float* bm1_e = (const float*)d_in[9];
  const float* Wm2_e = (const float*)d_in[10];
  const float* bm2_e = (const float*)d_in[11];
  const float* Wu1   = (const float*)d_in[12];
  const float* bu1   = (const float*)d_in[13];
  const float* Wu2   = (const float*)d_in[14];
  const float* bu2   = (const float*)d_in[15];
  const float* lnw   = (const float*)d_in[16];
  const float* lnb   = (const float*)d_in[17];
  const float* Wr    = (const float*)d_in[18];
  const float* br    = (const float*)d_in[19];
  const float* Wg1   = (const float*)d_in[20];
  const float* bg1   = (const float*)d_in[21];
  const float* Wg2   = (const float*)d_in[22];
  const float* bg2   = (const float*)d_in[23];

  const int MU_ = in_sizes[0];          // 100000
  const int ME_ = in_sizes[1] / 2;      // 200000
  const int NN  = in_sizes[2];          // 50000
  const int GN  = 100;
  const int NPG = NN / GN;              // 500 nodes per graph (contiguous)
  const int M2  = 2 * ME_;              // 400000 edge message slots
  const int NB  = (NN + 255) / 256;     // scan blocks (196 <= 256)
  const int NBW = (NN + 256) / 256;     // k_wstart covers i = 0..NN
  const int NBU = (NN + 63) / 64;       // k_update blocks (782)

  // ---- workspace layout ----
  float* h       = (float*)d_out;
  float* agg     = (float*)d_ws;                           // [N*64]
  float* g       = agg + (size_t)NN * E;                   // [G*64]
  float* mu0     = g + (size_t)GN * E;                     // [64]
  float* me0     = mu0 + 64;                               // [128]
  float* msgbuf  = me0 + TWO_E;                            // [M2*64]
  int*   cpos0   = (int*)(msgbuf + (size_t)M2 * E);        // [N]
  int*   cpos1   = cpos0 + NN;                             // [N]
  int*   cnt_u   = cpos1 + NN;                             // [N]
  int*   startp  = cnt_u + NN;                             // [N+1]
  int*   startp0 = startp + NN + 1;                        // [N+1]
  int*   startp1 = startp0 + NN + 1;                       // [N+1]
  int*   cur0    = startp1 + NN + 1;                       // [N+1]
  int*   cur1    = cur0 + NN + 1;                          // [N+1]
  int*   ord0    = cur1 + NN + 1;                          // [ME]
  int*   pos0    = ord0 + ME_;                             // [ME]
  int*   posE1   = pos0 + ME_;                             // [ME]
  int*   bsum    = posE1 + ME_;                            // [2*NB]
  int*   boff    = bsum + 2 * NB;                          // [2*NB]
  size_t int_end = (size_t)(boff + 2 * NB - (int*)d_ws);
  size_t pab_off = (int_end + 3) & ~(size_t)3;
  float* Pab     = (float*)d_ws + pab_off;                 // [N*256]
  size_t need_pab = (pab_off + (size_t)NN * 256) * 4;
  const bool pab_mode = (ws_size >= need_pab);

  { // h = 0
    int n4 = NN * E / 4;
    k_zero<<<(n4 + 255) / 256, 256, 0, stream>>>((float4*)h, n4);
  }
  { // zero [cpos0, cpos1, cnt_u] (3N ints; small spill into startp is ok)
    int n4 = (3 * NN + 4) / 4;
    k_zero<<<(n4 + 255) / 256, 256, 0, stream>>>((float4*)cpos0, n4);
  }
  // ---- CSR + counts + constant messages (once; graph static) ----
  k_count_e<<<(ME_ + 255) / 256, 256, 0, stream>>>(rel_e, cpos0, cpos1, ME_);
  k_count_u<<<(MU_ + 255) / 256, 256, 0, stream>>>(rel_u, cnt_u, MU_);
  k_bsum<<<NB, 256, 0, stream>>>(cpos0, cpos1, bsum, NN, NB);
  k_scanblk<<<1, 256, 0, stream>>>(bsum, boff, NB);
  k_wstart<<<NBW, 256, 0, stream>>>(cpos0, cpos1, boff, startp, startp0, startp1,
                                    cur0, cur1, NN, NB, ME_);
  k_fill_e<<<(ME_ + 255) / 256, 256, 0, stream>>>(
      rel_e, startp, startp0, startp1, cpos0, cur0, cur1, ord0, pos0, posE1, ME_);
  k_mlp0<<<1, 128, 0, stream>>>(bm1_u, Wm2_u, bm2_u, bm1_e, Wm2_e, bm2_e,
                                br, mu0, me0, g, GN);

  // ---- layer 0: messages constant; g = br; update emits unary agg + Pab ----
  k_agg0<<<(NN * 16 + 255) / 256, 256, 0, stream>>>(cnt_u, cpos0, cpos1, mu0, me0, agg, NN);
  k_update<true><<<NBU, 256, 0, stream>>>(
      h, agg, g, gids, Wu1, bu1, Wu2, bu2, Wg1, bg1, Wg2, bg2, lnw, lnb,
      cnt_u, Wm1_u, bm1_u, Wm2_u, bm2_u, Wm1_e, bm1_e, Pab, pab_mode ? 1 : 0, NN);

  // ---- layers 1..3 ----
  for (int l = 1; l < 4; ++l) {
    if (pab_mode)
      k_edge_pab<<<(ME_ + 63) / 64, 512, 0, stream>>>(
          rel_e, ord0, pos0, posE1, Pab, Wm2_e, bm2_e, msgbuf, ME_);
    else
      k_edge_fb<<<(ME_ + 63) / 64, 256, 0, stream>>>(
          rel_e, ord0, pos0, posE1, h, Wm1_e, bm1_e, Wm2_e, bm2_e, msgbuf, ME_);
    k_gather<<<(NN + 3) / 4, 256, 0, stream>>>(msgbuf, startp, agg, NN);
    k_readout_g<<<GN, 256, 0, stream>>>(h, gids, Wr, br, g, NN, NPG);
    if (l < 3)
      k_update<true><<<NBU, 256, 0, stream>>>(
          h, agg, g, gids, Wu1, bu1, Wu2, bu2, Wg1, bg1, Wg2, bg2, lnw, lnb,
          cnt_u, Wm1_u, bm1_u, Wm2_u, bm2_u, Wm1_e, bm1_e, Pab, pab_mode ? 1 : 0, NN);
    else
      k_update<false><<<NBU, 256, 0, stream>>>(
          h, agg, g, gids, Wu1, bu1, Wu2, bu2, Wg1, bg1, Wg2, bg2, lnw, lnb,
          cnt_u, Wm1_u, bm1_u, Wm2_u, bm2_u, Wm1_e, bm1_e, Pab, 0, NN);
  }
}